// Round 5
// baseline (583.943 us; speedup 1.0000x reference)
//
#include <hip/hip_runtime.h>

#define NROWS 65536
#define KCODES 1024
#define DDIM 256

// output offsets in floats (concat of reference return tuple)
#define Q_OFF    0
#define LOSS_OFF 16777216
#define PERP_OFF 16777217
#define IND_OFF  16777218
#define DIST_OFF 16842754

#define MARGIN  4e-4f
#define MAXCAND 16
#define RG_BLOCKS (NROWS / 4)

typedef unsigned long long u64;
typedef unsigned int u32;
typedef unsigned short u16;
typedef __attribute__((ext_vector_type(8))) short bf16x8;
typedef __attribute__((ext_vector_type(4))) float f32x4;

// RNE float->bf16 bits (no NaN handling; inputs are tame)
__device__ inline u32 f2bf_bits(float f) {
    u32 u = __float_as_uint(f);
    return (u + 0x7fffu + ((u >> 16) & 1u)) >> 16;
}
__device__ inline float bf2f(u32 bits) { return __uint_as_float(bits << 16); }

// ---------------- init workspace ----------------------------------------------
__global__ __launch_bounds__(256) void init_kernel(u32* __restrict__ cand_cnt,
                                                   u32* __restrict__ hist) {
    int i = blockIdx.x * 256 + threadIdx.x;
    if (i < NROWS) cand_cnt[i] = 0u;
    if (i < KCODES) hist[i] = 0u;
}

// ---------------- squared norms (fp32, epilogue + refine both reuse these) ----
__global__ __launch_bounds__(256) void sqnorm_kernel(
    const float* __restrict__ lat, const float* __restrict__ emb,
    float* __restrict__ row_sq, float* __restrict__ emb_sq) {
    int gwave = (blockIdx.x * 256 + threadIdx.x) >> 6;
    int lane = threadIdx.x & 63;
    if (gwave >= NROWS + KCODES) return;
    const float* src = (gwave < NROWS) ? lat + (size_t)gwave * DDIM
                                       : emb + (size_t)(gwave - NROWS) * DDIM;
    float4 v = *reinterpret_cast<const float4*>(src + lane * 4);
    float s = v.x * v.x + v.y * v.y + v.z * v.z + v.w * v.w;
#pragma unroll
    for (int m = 32; m >= 1; m >>= 1) s += __shfl_xor(s, m, 64);
    if (lane == 0) {
        if (gwave < NROWS) row_sq[gwave] = s;
        else emb_sq[gwave - NROWS] = s;
    }
}

// -------- one-shot fp32 -> (bf16 hi, bf16 lo) split of lat and emb ------------
__global__ __launch_bounds__(256) void convert_kernel(
    const float* __restrict__ lat, const float* __restrict__ emb,
    u16* __restrict__ Ahg, u16* __restrict__ Alg,
    u16* __restrict__ Bhg, u16* __restrict__ Blg) {
    const int NA = NROWS * DDIM / 4;
    const int NB = KCODES * DDIM / 4;
    for (int i = blockIdx.x * 256 + threadIdx.x; i < NA + NB; i += gridDim.x * 256) {
        const float* src;
        u16 *dh, *dl;
        int j;
        if (i < NA) { src = lat; dh = Ahg; dl = Alg; j = i; }
        else        { src = emb; dh = Bhg; dl = Blg; j = i - NA; }
        float4 v = reinterpret_cast<const float4*>(src)[j];
        u32 h0 = f2bf_bits(v.x), h1 = f2bf_bits(v.y), h2 = f2bf_bits(v.z), h3 = f2bf_bits(v.w);
        u32 l0 = f2bf_bits(v.x - bf2f(h0)), l1 = f2bf_bits(v.y - bf2f(h1));
        u32 l2 = f2bf_bits(v.z - bf2f(h2)), l3 = f2bf_bits(v.w - bf2f(h3));
        reinterpret_cast<uint2*>(dh)[j] = make_uint2(h0 | (h1 << 16), h2 | (h3 << 16));
        reinterpret_cast<uint2*>(dl)[j] = make_uint2(l0 | (l1 << 16), l2 | (l3 << 16));
    }
}

// ---------------- dist via bf16-split MFMA, pre-converted inputs --------------
// Bit-identical dv values vs the in-kernel-convert version (same split, same
// MFMA order). 128x128 tile, 4 waves, BK=32, reg-staged bf16 loads.
__global__ __launch_bounds__(256, 2) void dist_mfma2_kernel(
    const u16* __restrict__ Ahg, const u16* __restrict__ Alg,
    const u16* __restrict__ Bhg, const u16* __restrict__ Blg,
    const float* __restrict__ row_sq, const float* __restrict__ emb_sq,
    float* __restrict__ dist, u32* __restrict__ cand_cnt, u16* __restrict__ cand) {
    __shared__ u16 Ah[128 * 40], Al[128 * 40], Bh[128 * 40], Bl[128 * 40];
    const int tid = threadIdx.x;
    const int lane = tid & 63, wid = tid >> 6;
    const int wr = wid >> 1, wc = wid & 1;       // wave quadrant (64x64)
    const int li = lane & 15, lg = lane >> 4;
    const int row0 = blockIdx.y * 128, col0 = blockIdx.x * 128;
    const int sr = tid >> 2, sub = tid & 3;      // staging: rows sr, sr+64; 16B chunk sub

    f32x4 acc[4][4];
#pragma unroll
    for (int mf = 0; mf < 4; ++mf)
#pragma unroll
        for (int nf = 0; nf < 4; ++nf) acc[mf][nf] = (f32x4)0.0f;

#define GLD(base, row, ks) \
    (*reinterpret_cast<const uint4*>((base) + (size_t)(row) * DDIM + (ks) * 32 + sub * 8))

    // prefetch K-step 0 into registers (2 rows per array per thread)
    uint4 pa0 = GLD(Ahg, row0 + sr, 0),      pa1 = GLD(Ahg, row0 + sr + 64, 0);
    uint4 pl0 = GLD(Alg, row0 + sr, 0),      pl1 = GLD(Alg, row0 + sr + 64, 0);
    uint4 pb0 = GLD(Bhg, col0 + sr, 0),      pb1 = GLD(Bhg, col0 + sr + 64, 0);
    uint4 pc0 = GLD(Blg, col0 + sr, 0),      pc1 = GLD(Blg, col0 + sr + 64, 0);

    for (int ks = 0; ks < 8; ++ks) {
        __syncthreads();  // previous iter's LDS reads done
        *reinterpret_cast<uint4*>(&Ah[sr * 40 + sub * 8]) = pa0;
        *reinterpret_cast<uint4*>(&Ah[(sr + 64) * 40 + sub * 8]) = pa1;
        *reinterpret_cast<uint4*>(&Al[sr * 40 + sub * 8]) = pl0;
        *reinterpret_cast<uint4*>(&Al[(sr + 64) * 40 + sub * 8]) = pl1;
        *reinterpret_cast<uint4*>(&Bh[sr * 40 + sub * 8]) = pb0;
        *reinterpret_cast<uint4*>(&Bh[(sr + 64) * 40 + sub * 8]) = pb1;
        *reinterpret_cast<uint4*>(&Bl[sr * 40 + sub * 8]) = pc0;
        *reinterpret_cast<uint4*>(&Bl[(sr + 64) * 40 + sub * 8]) = pc1;
        if (ks < 7) {
            pa0 = GLD(Ahg, row0 + sr, ks + 1);  pa1 = GLD(Ahg, row0 + sr + 64, ks + 1);
            pl0 = GLD(Alg, row0 + sr, ks + 1);  pl1 = GLD(Alg, row0 + sr + 64, ks + 1);
            pb0 = GLD(Bhg, col0 + sr, ks + 1);  pb1 = GLD(Bhg, col0 + sr + 64, ks + 1);
            pc0 = GLD(Blg, col0 + sr, ks + 1);  pc1 = GLD(Blg, col0 + sr + 64, ks + 1);
        }
        __syncthreads();
        // fragment reads: A row = li, k = lg*8 + 0..7
        bf16x8 fah[4], fal[4], fbh[4], fbl[4];
        int k0 = lg * 8;
#pragma unroll
        for (int mf = 0; mf < 4; ++mf) {
            int r = wr * 64 + mf * 16 + li;
            fah[mf] = *reinterpret_cast<const bf16x8*>(&Ah[r * 40 + k0]);
            fal[mf] = *reinterpret_cast<const bf16x8*>(&Al[r * 40 + k0]);
        }
#pragma unroll
        for (int nf = 0; nf < 4; ++nf) {
            int c = wc * 64 + nf * 16 + li;
            fbh[nf] = *reinterpret_cast<const bf16x8*>(&Bh[c * 40 + k0]);
            fbl[nf] = *reinterpret_cast<const bf16x8*>(&Bl[c * 40 + k0]);
        }
#pragma unroll
        for (int mf = 0; mf < 4; ++mf)
#pragma unroll
            for (int nf = 0; nf < 4; ++nf) {
                acc[mf][nf] = __builtin_amdgcn_mfma_f32_16x16x32_bf16(fah[mf], fbh[nf], acc[mf][nf], 0, 0, 0);
                acc[mf][nf] = __builtin_amdgcn_mfma_f32_16x16x32_bf16(fah[mf], fbl[nf], acc[mf][nf], 0, 0, 0);
                acc[mf][nf] = __builtin_amdgcn_mfma_f32_16x16x32_bf16(fal[mf], fbh[nf], acc[mf][nf], 0, 0, 0);
            }
    }
#undef GLD

    // ---------------- epilogue: dist write + block-local row-min + candidates --
    __syncthreads();
    float* rs_lds = reinterpret_cast<float*>(Ah);      // 128 f
    float* es_lds = rs_lds + 128;                      // 128 f
    float* rowmin_lds = es_lds + 128;                  // 128 f
    if (tid < 128) rs_lds[tid] = row_sq[row0 + tid];
    else if (tid < 256) es_lds[tid - 128] = emb_sq[col0 + tid - 128];
    __syncthreads();

    // C/D layout: row = (lane>>4)*4 + reg, col = lane&15 (per 16x16 frag)
    float rmin[16];
#pragma unroll
    for (int mf = 0; mf < 4; ++mf)
#pragma unroll
        for (int rg = 0; rg < 4; ++rg) {
            int rl = wr * 64 + mf * 16 + lg * 4 + rg;
            float rs = rs_lds[rl];
            float best = 3.4e38f;
#pragma unroll
            for (int nf = 0; nf < 4; ++nf) {
                int cl = wc * 64 + nf * 16 + li;
                float dv = (rs + es_lds[cl]) - 2.0f * acc[mf][nf][rg];
                dist[(size_t)(row0 + rl) * KCODES + col0 + cl] = dv;
                best = fminf(best, dv);
            }
            rmin[mf * 4 + rg] = best;
        }
#pragma unroll
    for (int m = 8; m >= 1; m >>= 1)
#pragma unroll
        for (int j = 0; j < 16; ++j) rmin[j] = fminf(rmin[j], __shfl_xor(rmin[j], m, 64));
    if (wc == 0 && li == 0) {
#pragma unroll
        for (int mf = 0; mf < 4; ++mf)
#pragma unroll
            for (int rg = 0; rg < 4; ++rg)
                rowmin_lds[wr * 64 + mf * 16 + lg * 4 + rg] = rmin[mf * 4 + rg];
    }
    __syncthreads();
    if (wc == 1 && li == 0) {
#pragma unroll
        for (int mf = 0; mf < 4; ++mf)
#pragma unroll
            for (int rg = 0; rg < 4; ++rg) {
                int rl = wr * 64 + mf * 16 + lg * 4 + rg;
                rowmin_lds[rl] = fminf(rowmin_lds[rl], rmin[mf * 4 + rg]);
            }
    }
    __syncthreads();
#pragma unroll
    for (int mf = 0; mf < 4; ++mf)
#pragma unroll
        for (int rg = 0; rg < 4; ++rg) {
            int rl = wr * 64 + mf * 16 + lg * 4 + rg;
            float thr = rowmin_lds[rl] + MARGIN;
            float rs = rs_lds[rl];
#pragma unroll
            for (int nf = 0; nf < 4; ++nf) {
                int cl = wc * 64 + nf * 16 + li;
                float dv = (rs + es_lds[cl]) - 2.0f * acc[mf][nf][rg];
                if (dv <= thr) {
                    int grow = row0 + rl;
                    u32 slot = atomicAdd(&cand_cnt[grow], 1u);
                    if (slot < MAXCAND) cand[(size_t)grow * MAXCAND + slot] = (u16)(col0 + cl);
                }
            }
        }
}

// ---------------- fallback: R4 in-kernel-convert version (small ws) -----------
__global__ __launch_bounds__(256, 2) void dist_mfma_kernel(
    const float* __restrict__ A, const float* __restrict__ B,
    const float* __restrict__ row_sq, const float* __restrict__ emb_sq,
    float* __restrict__ dist, u32* __restrict__ cand_cnt, u16* __restrict__ cand) {
    __shared__ u16 Ah[128 * 40], Al[128 * 40], Bh[128 * 40], Bl[128 * 40];
    const int tid = threadIdx.x;
    const int lane = tid & 63, wid = tid >> 6;
    const int wr = wid >> 1, wc = wid & 1;
    const int li = lane & 15, lg = lane >> 4;
    const int row0 = blockIdx.y * 128, col0 = blockIdx.x * 128;
    const int rbase = tid >> 3, c4 = tid & 7;

    f32x4 acc[4][4];
#pragma unroll
    for (int mf = 0; mf < 4; ++mf)
#pragma unroll
        for (int nf = 0; nf < 4; ++nf) acc[mf][nf] = (f32x4)0.0f;

    float4 ra[4], rb[4];
#pragma unroll
    for (int i = 0; i < 4; ++i) {
        int r = rbase + i * 32;
        ra[i] = *reinterpret_cast<const float4*>(A + (size_t)(row0 + r) * DDIM + c4 * 4);
        rb[i] = *reinterpret_cast<const float4*>(B + (size_t)(col0 + r) * DDIM + c4 * 4);
    }

    for (int ks = 0; ks < 8; ++ks) {
        __syncthreads();
#pragma unroll
        for (int i = 0; i < 4; ++i) {
            int r = rbase + i * 32;
            float av[4] = {ra[i].x, ra[i].y, ra[i].z, ra[i].w};
            float bv[4] = {rb[i].x, rb[i].y, rb[i].z, rb[i].w};
            u32 ahb[4], alb[4], bhb[4], blb[4];
#pragma unroll
            for (int j = 0; j < 4; ++j) {
                ahb[j] = f2bf_bits(av[j]);
                alb[j] = f2bf_bits(av[j] - bf2f(ahb[j]));
                bhb[j] = f2bf_bits(bv[j]);
                blb[j] = f2bf_bits(bv[j] - bf2f(bhb[j]));
            }
            int o = r * 40 + c4 * 4;
            *reinterpret_cast<uint2*>(&Ah[o]) = make_uint2(ahb[0] | (ahb[1] << 16), ahb[2] | (ahb[3] << 16));
            *reinterpret_cast<uint2*>(&Al[o]) = make_uint2(alb[0] | (alb[1] << 16), alb[2] | (alb[3] << 16));
            *reinterpret_cast<uint2*>(&Bh[o]) = make_uint2(bhb[0] | (bhb[1] << 16), bhb[2] | (bhb[3] << 16));
            *reinterpret_cast<uint2*>(&Bl[o]) = make_uint2(blb[0] | (blb[1] << 16), blb[2] | (blb[3] << 16));
        }
        if (ks < 7) {
            int d0 = (ks + 1) * 32;
#pragma unroll
            for (int i = 0; i < 4; ++i) {
                int r = rbase + i * 32;
                ra[i] = *reinterpret_cast<const float4*>(A + (size_t)(row0 + r) * DDIM + d0 + c4 * 4);
                rb[i] = *reinterpret_cast<const float4*>(B + (size_t)(col0 + r) * DDIM + d0 + c4 * 4);
            }
        }
        __syncthreads();
        bf16x8 fah[4], fal[4], fbh[4], fbl[4];
        int k0 = lg * 8;
#pragma unroll
        for (int mf = 0; mf < 4; ++mf) {
            int r = wr * 64 + mf * 16 + li;
            fah[mf] = *reinterpret_cast<const bf16x8*>(&Ah[r * 40 + k0]);
            fal[mf] = *reinterpret_cast<const bf16x8*>(&Al[r * 40 + k0]);
        }
#pragma unroll
        for (int nf = 0; nf < 4; ++nf) {
            int c = wc * 64 + nf * 16 + li;
            fbh[nf] = *reinterpret_cast<const bf16x8*>(&Bh[c * 40 + k0]);
            fbl[nf] = *reinterpret_cast<const bf16x8*>(&Bl[c * 40 + k0]);
        }
#pragma unroll
        for (int mf = 0; mf < 4; ++mf)
#pragma unroll
            for (int nf = 0; nf < 4; ++nf) {
                acc[mf][nf] = __builtin_amdgcn_mfma_f32_16x16x32_bf16(fah[mf], fbh[nf], acc[mf][nf], 0, 0, 0);
                acc[mf][nf] = __builtin_amdgcn_mfma_f32_16x16x32_bf16(fah[mf], fbl[nf], acc[mf][nf], 0, 0, 0);
                acc[mf][nf] = __builtin_amdgcn_mfma_f32_16x16x32_bf16(fal[mf], fbh[nf], acc[mf][nf], 0, 0, 0);
            }
    }

    __syncthreads();
    float* rs_lds = reinterpret_cast<float*>(Ah);
    float* es_lds = rs_lds + 128;
    float* rowmin_lds = es_lds + 128;
    if (tid < 128) rs_lds[tid] = row_sq[row0 + tid];
    else if (tid < 256) es_lds[tid - 128] = emb_sq[col0 + tid - 128];
    __syncthreads();

    float rmin[16];
#pragma unroll
    for (int mf = 0; mf < 4; ++mf)
#pragma unroll
        for (int rg = 0; rg < 4; ++rg) {
            int rl = wr * 64 + mf * 16 + lg * 4 + rg;
            float rs = rs_lds[rl];
            float best = 3.4e38f;
#pragma unroll
            for (int nf = 0; nf < 4; ++nf) {
                int cl = wc * 64 + nf * 16 + li;
                float dv = (rs + es_lds[cl]) - 2.0f * acc[mf][nf][rg];
                dist[(size_t)(row0 + rl) * KCODES + col0 + cl] = dv;
                best = fminf(best, dv);
            }
            rmin[mf * 4 + rg] = best;
        }
#pragma unroll
    for (int m = 8; m >= 1; m >>= 1)
#pragma unroll
        for (int j = 0; j < 16; ++j) rmin[j] = fminf(rmin[j], __shfl_xor(rmin[j], m, 64));
    if (wc == 0 && li == 0) {
#pragma unroll
        for (int mf = 0; mf < 4; ++mf)
#pragma unroll
            for (int rg = 0; rg < 4; ++rg)
                rowmin_lds[wr * 64 + mf * 16 + lg * 4 + rg] = rmin[mf * 4 + rg];
    }
    __syncthreads();
    if (wc == 1 && li == 0) {
#pragma unroll
        for (int mf = 0; mf < 4; ++mf)
#pragma unroll
            for (int rg = 0; rg < 4; ++rg) {
                int rl = wr * 64 + mf * 16 + lg * 4 + rg;
                rowmin_lds[rl] = fminf(rowmin_lds[rl], rmin[mf * 4 + rg]);
            }
    }
    __syncthreads();
#pragma unroll
    for (int mf = 0; mf < 4; ++mf)
#pragma unroll
        for (int rg = 0; rg < 4; ++rg) {
            int rl = wr * 64 + mf * 16 + lg * 4 + rg;
            float thr = rowmin_lds[rl] + MARGIN;
            float rs = rs_lds[rl];
#pragma unroll
            for (int nf = 0; nf < 4; ++nf) {
                int cl = wc * 64 + nf * 16 + li;
                float dv = (rs + es_lds[cl]) - 2.0f * acc[mf][nf][rg];
                if (dv <= thr) {
                    int grow = row0 + rl;
                    u32 slot = atomicAdd(&cand_cnt[grow], 1u);
                    if (slot < MAXCAND) cand[(size_t)grow * MAXCAND + slot] = (u16)(col0 + cl);
                }
            }
        }
}

// ------- refine: reproduce the fp32 serial-FMA comparison BIT-EXACTLY ---------
// Unrolled with 1-deep prefetch; FMA chain order (and thus bits) unchanged.
__global__ __launch_bounds__(256) void refine_gather_kernel(
    const float* __restrict__ lat, const float* __restrict__ emb,
    const float* __restrict__ row_sq, const float* __restrict__ emb_sq,
    const u32* __restrict__ cand_cnt, const u16* __restrict__ cand,
    float* __restrict__ qout, float* __restrict__ indout,
    u32* __restrict__ hist, float* __restrict__ loss_part) {
    __shared__ float xs[4][260];
    __shared__ float lred[4];
    const int wave = threadIdx.x >> 6, lane = threadIdx.x & 63;
    const int row = blockIdx.x * 4 + wave;

    float4 xv = *reinterpret_cast<const float4*>(lat + (size_t)row * DDIM + lane * 4);
    *reinterpret_cast<float4*>(&xs[wave][lane * 4]) = xv;
    __syncthreads();

    int cnt = (int)cand_cnt[row];
    if (cnt > MAXCAND) cnt = MAXCAND;
    int slot = lane & 15;
    if (slot >= cnt) slot = 0;   // cnt >= 1 always (block-min is recorded)
    int c = cand[(size_t)row * MAXCAND + slot];

    const float* erow = emb + (size_t)c * DDIM;
    float4 ev = *reinterpret_cast<const float4*>(erow);
    float acc = 0.0f;
#pragma unroll
    for (int k4 = 0; k4 < 64; ++k4) {
        float4 cur = ev;
        if (k4 < 63) ev = *reinterpret_cast<const float4*>(erow + (k4 + 1) * 4);
        float4 xq = *reinterpret_cast<const float4*>(&xs[wave][k4 * 4]);
        acc = __builtin_fmaf(xq.x, cur.x, acc);
        acc = __builtin_fmaf(xq.y, cur.y, acc);
        acc = __builtin_fmaf(xq.z, cur.z, acc);
        acc = __builtin_fmaf(xq.w, cur.w, acc);
    }
    float t = row_sq[row] + emb_sq[c];
    float dv = __builtin_fmaf(-2.0f, acc, t);   // == t - 2*acc exactly (x2 exact)

    // lexicographic (dv, index) min over the wave -> fp32 argmin, first-index tie
#pragma unroll
    for (int m = 32; m >= 1; m >>= 1) {
        float od = __shfl_xor(dv, m, 64);
        int oc = __shfl_xor(c, m, 64);
        if (od < dv || (od == dv && oc < c)) { dv = od; c = oc; }
    }
    int bestc = c;

    float4 ev2 = *reinterpret_cast<const float4*>(emb + (size_t)bestc * DDIM + lane * 4);
    float dx = ev2.x - xv.x, dy = ev2.y - xv.y, dz = ev2.z - xv.z, dw = ev2.w - xv.w;
    float4 q = make_float4(xv.x + dx, xv.y + dy, xv.z + dz, xv.w + dw);
    *reinterpret_cast<float4*>(qout + (size_t)row * DDIM + lane * 4) = q;
    float s = dx * dx + dy * dy + dz * dz + dw * dw;
#pragma unroll
    for (int m = 32; m >= 1; m >>= 1) s += __shfl_xor(s, m, 64);
    if (lane == 0) {
        lred[wave] = s;
        atomicAdd(&hist[bestc], 1u);
        indout[row] = (float)bestc;
    }
    __syncthreads();
    if (threadIdx.x == 0)
        loss_part[blockIdx.x] = (lred[0] + lred[1]) + (lred[2] + lred[3]);
}

// ---------------- scalars: vq_loss (reduce partials), perplexity ---------------
__global__ __launch_bounds__(1024) void scalar_kernel(
    const u32* __restrict__ hist, const float* __restrict__ loss_part,
    float* __restrict__ out_loss, float* __restrict__ out_perp) {
    __shared__ double lred[16];
    __shared__ float ered[16];
    int t = threadIdx.x;
    double ls = 0.0;
#pragma unroll
    for (int i = 0; i < RG_BLOCKS / 1024; ++i)
        ls += (double)loss_part[t + i * 1024];
    float p = (float)hist[t] / 65536.0f;
    float es = p * logf(p + 1e-10f);
#pragma unroll
    for (int m = 32; m >= 1; m >>= 1) {
        ls += __shfl_xor(ls, m, 64);
        es += __shfl_xor(es, m, 64);
    }
    if ((t & 63) == 0) { lred[t >> 6] = ls; ered[t >> 6] = es; }
    __syncthreads();
    if (t < 64) {
        double lv = (t < 16) ? lred[t] : 0.0;
        float ev = (t < 16) ? ered[t] : 0.0f;
#pragma unroll
        for (int m = 32; m >= 1; m >>= 1) {
            lv += __shfl_xor(lv, m, 64);
            ev += __shfl_xor(ev, m, 64);
        }
        if (t == 0) {
            *out_perp = expf(-ev);
            double ml = lv / (double)((size_t)NROWS * DDIM);
            *out_loss = (float)(ml * 0.25 + ml);  // beta*commit + delta*embed (equal)
        }
    }
}

extern "C" void kernel_launch(void* const* d_in, const int* in_sizes, int n_in,
                              void* d_out, int out_size, void* d_ws, size_t ws_size,
                              hipStream_t stream) {
    const float* lat = (const float*)d_in[0];
    const float* emb = (const float*)d_in[1];
    float* out = (float*)d_out;
    char* ws = (char*)d_ws;

    u32* cand_cnt = (u32*)ws;                          // 262144 B
    u16* cand = (u16*)(ws + 262144);                   // 2097152 B
    float* row_sq = (float*)(ws + 2359296);            // 262144 B
    float* emb_sq = (float*)(ws + 2621440);            // 4096 B
    u32* hist = (u32*)(ws + 2625536);                  // 4096 B
    float* loss_part = (float*)(ws + 2629632);         // 65536 B
    u16* Ahg = (u16*)(ws + 2695168);                   // 33554432 B
    u16* Alg = (u16*)(ws + 36249600);                  // 33554432 B
    u16* Bhg = (u16*)(ws + 69804032);                  // 524288 B
    u16* Blg = (u16*)(ws + 70328320);                  // 524288 B
    const size_t WS_NEED = 70852608;

    init_kernel<<<256, 256, 0, stream>>>(cand_cnt, hist);
    sqnorm_kernel<<<(NROWS + KCODES) / 4, 256, 0, stream>>>(lat, emb, row_sq, emb_sq);
    dim3 grid(KCODES / 128, NROWS / 128);
    if (ws_size >= WS_NEED) {
        convert_kernel<<<2048, 256, 0, stream>>>(lat, emb, Ahg, Alg, Bhg, Blg);
        dist_mfma2_kernel<<<grid, 256, 0, stream>>>(Ahg, Alg, Bhg, Blg, row_sq, emb_sq,
                                                    out + DIST_OFF, cand_cnt, cand);
    } else {
        dist_mfma_kernel<<<grid, 256, 0, stream>>>(lat, emb, row_sq, emb_sq,
                                                   out + DIST_OFF, cand_cnt, cand);
    }
    refine_gather_kernel<<<RG_BLOCKS, 256, 0, stream>>>(lat, emb, row_sq, emb_sq,
                                                        cand_cnt, cand,
                                                        out + Q_OFF, out + IND_OFF,
                                                        hist, loss_part);
    scalar_kernel<<<1, 1024, 0, stream>>>(hist, loss_part,
                                          out + LOSS_OFF, out + PERP_OFF);
}

// Round 6
// 384.546 us; speedup vs baseline: 1.5185x; 1.5185x over previous
//
#include <hip/hip_runtime.h>

#define NROWS 65536
#define KCODES 1024
#define DDIM 256

// output offsets in floats (concat of reference return tuple)
#define Q_OFF    0
#define LOSS_OFF 16777216
#define PERP_OFF 16777217
#define IND_OFF  16777218
#define DIST_OFF 16842754

#define MARGIN  4e-4f
#define MAXCAND 16
#define RG_BLOCKS (NROWS / 16)   // 4096 blocks, 16 rows each

typedef unsigned long long u64;
typedef unsigned int u32;
typedef unsigned short u16;
typedef __attribute__((ext_vector_type(8))) short bf16x8;
typedef __attribute__((ext_vector_type(4))) float f32x4;

// RNE float->bf16 bits (no NaN handling; inputs are tame)
__device__ inline u32 f2bf_bits(float f) {
    u32 u = __float_as_uint(f);
    return (u + 0x7fffu + ((u >> 16) & 1u)) >> 16;
}
__device__ inline float bf2f(u32 bits) { return __uint_as_float(bits << 16); }

// ---------------- init workspace ----------------------------------------------
__global__ __launch_bounds__(256) void init_kernel(u32* __restrict__ cand_cnt,
                                                   u32* __restrict__ hist) {
    int i = blockIdx.x * 256 + threadIdx.x;
    if (i < NROWS) cand_cnt[i] = 0u;
    if (i < KCODES) hist[i] = 0u;
}

// ---------------- squared norms (fp32, epilogue + refine both reuse these) ----
__global__ __launch_bounds__(256) void sqnorm_kernel(
    const float* __restrict__ lat, const float* __restrict__ emb,
    float* __restrict__ row_sq, float* __restrict__ emb_sq) {
    int gwave = (blockIdx.x * 256 + threadIdx.x) >> 6;
    int lane = threadIdx.x & 63;
    if (gwave >= NROWS + KCODES) return;
    const float* src = (gwave < NROWS) ? lat + (size_t)gwave * DDIM
                                       : emb + (size_t)(gwave - NROWS) * DDIM;
    float4 v = *reinterpret_cast<const float4*>(src + lane * 4);
    float s = v.x * v.x + v.y * v.y + v.z * v.z + v.w * v.w;
#pragma unroll
    for (int m = 32; m >= 1; m >>= 1) s += __shfl_xor(s, m, 64);
    if (lane == 0) {
        if (gwave < NROWS) row_sq[gwave] = s;
        else emb_sq[gwave - NROWS] = s;
    }
}

// -------- one-shot fp32 -> (bf16 hi, bf16 lo) split of lat and emb ------------
__global__ __launch_bounds__(256) void convert_kernel(
    const float* __restrict__ lat, const float* __restrict__ emb,
    u16* __restrict__ Ahg, u16* __restrict__ Alg,
    u16* __restrict__ Bhg, u16* __restrict__ Blg) {
    const int NA = NROWS * DDIM / 4;
    const int NB = KCODES * DDIM / 4;
    for (int i = blockIdx.x * 256 + threadIdx.x; i < NA + NB; i += gridDim.x * 256) {
        const float* src;
        u16 *dh, *dl;
        int j;
        if (i < NA) { src = lat; dh = Ahg; dl = Alg; j = i; }
        else        { src = emb; dh = Bhg; dl = Blg; j = i - NA; }
        float4 v = reinterpret_cast<const float4*>(src)[j];
        u32 h0 = f2bf_bits(v.x), h1 = f2bf_bits(v.y), h2 = f2bf_bits(v.z), h3 = f2bf_bits(v.w);
        u32 l0 = f2bf_bits(v.x - bf2f(h0)), l1 = f2bf_bits(v.y - bf2f(h1));
        u32 l2 = f2bf_bits(v.z - bf2f(h2)), l3 = f2bf_bits(v.w - bf2f(h3));
        reinterpret_cast<uint2*>(dh)[j] = make_uint2(h0 | (h1 << 16), h2 | (h3 << 16));
        reinterpret_cast<uint2*>(dl)[j] = make_uint2(l0 | (l1 << 16), l2 | (l3 << 16));
    }
}

// ---------------- dist via bf16-split MFMA, pre-converted inputs --------------
__global__ __launch_bounds__(256, 2) void dist_mfma2_kernel(
    const u16* __restrict__ Ahg, const u16* __restrict__ Alg,
    const u16* __restrict__ Bhg, const u16* __restrict__ Blg,
    const float* __restrict__ row_sq, const float* __restrict__ emb_sq,
    float* __restrict__ dist, u32* __restrict__ cand_cnt, u16* __restrict__ cand) {
    __shared__ u16 Ah[128 * 40], Al[128 * 40], Bh[128 * 40], Bl[128 * 40];
    const int tid = threadIdx.x;
    const int lane = tid & 63, wid = tid >> 6;
    const int wr = wid >> 1, wc = wid & 1;       // wave quadrant (64x64)
    const int li = lane & 15, lg = lane >> 4;
    const int row0 = blockIdx.y * 128, col0 = blockIdx.x * 128;
    const int sr = tid >> 2, sub = tid & 3;      // staging: rows sr, sr+64; 16B chunk sub

    f32x4 acc[4][4];
#pragma unroll
    for (int mf = 0; mf < 4; ++mf)
#pragma unroll
        for (int nf = 0; nf < 4; ++nf) acc[mf][nf] = (f32x4)0.0f;

#define GLD(base, row, ks) \
    (*reinterpret_cast<const uint4*>((base) + (size_t)(row) * DDIM + (ks) * 32 + sub * 8))

    uint4 pa0 = GLD(Ahg, row0 + sr, 0),      pa1 = GLD(Ahg, row0 + sr + 64, 0);
    uint4 pl0 = GLD(Alg, row0 + sr, 0),      pl1 = GLD(Alg, row0 + sr + 64, 0);
    uint4 pb0 = GLD(Bhg, col0 + sr, 0),      pb1 = GLD(Bhg, col0 + sr + 64, 0);
    uint4 pc0 = GLD(Blg, col0 + sr, 0),      pc1 = GLD(Blg, col0 + sr + 64, 0);

    for (int ks = 0; ks < 8; ++ks) {
        __syncthreads();  // previous iter's LDS reads done
        *reinterpret_cast<uint4*>(&Ah[sr * 40 + sub * 8]) = pa0;
        *reinterpret_cast<uint4*>(&Ah[(sr + 64) * 40 + sub * 8]) = pa1;
        *reinterpret_cast<uint4*>(&Al[sr * 40 + sub * 8]) = pl0;
        *reinterpret_cast<uint4*>(&Al[(sr + 64) * 40 + sub * 8]) = pl1;
        *reinterpret_cast<uint4*>(&Bh[sr * 40 + sub * 8]) = pb0;
        *reinterpret_cast<uint4*>(&Bh[(sr + 64) * 40 + sub * 8]) = pb1;
        *reinterpret_cast<uint4*>(&Bl[sr * 40 + sub * 8]) = pc0;
        *reinterpret_cast<uint4*>(&Bl[(sr + 64) * 40 + sub * 8]) = pc1;
        if (ks < 7) {
            pa0 = GLD(Ahg, row0 + sr, ks + 1);  pa1 = GLD(Ahg, row0 + sr + 64, ks + 1);
            pl0 = GLD(Alg, row0 + sr, ks + 1);  pl1 = GLD(Alg, row0 + sr + 64, ks + 1);
            pb0 = GLD(Bhg, col0 + sr, ks + 1);  pb1 = GLD(Bhg, col0 + sr + 64, ks + 1);
            pc0 = GLD(Blg, col0 + sr, ks + 1);  pc1 = GLD(Blg, col0 + sr + 64, ks + 1);
        }
        __syncthreads();
        bf16x8 fah[4], fal[4], fbh[4], fbl[4];
        int k0 = lg * 8;
#pragma unroll
        for (int mf = 0; mf < 4; ++mf) {
            int r = wr * 64 + mf * 16 + li;
            fah[mf] = *reinterpret_cast<const bf16x8*>(&Ah[r * 40 + k0]);
            fal[mf] = *reinterpret_cast<const bf16x8*>(&Al[r * 40 + k0]);
        }
#pragma unroll
        for (int nf = 0; nf < 4; ++nf) {
            int c = wc * 64 + nf * 16 + li;
            fbh[nf] = *reinterpret_cast<const bf16x8*>(&Bh[c * 40 + k0]);
            fbl[nf] = *reinterpret_cast<const bf16x8*>(&Bl[c * 40 + k0]);
        }
#pragma unroll
        for (int mf = 0; mf < 4; ++mf)
#pragma unroll
            for (int nf = 0; nf < 4; ++nf) {
                acc[mf][nf] = __builtin_amdgcn_mfma_f32_16x16x32_bf16(fah[mf], fbh[nf], acc[mf][nf], 0, 0, 0);
                acc[mf][nf] = __builtin_amdgcn_mfma_f32_16x16x32_bf16(fah[mf], fbl[nf], acc[mf][nf], 0, 0, 0);
                acc[mf][nf] = __builtin_amdgcn_mfma_f32_16x16x32_bf16(fal[mf], fbh[nf], acc[mf][nf], 0, 0, 0);
            }
    }
#undef GLD

    // ---------------- epilogue: dist write + block-local row-min + candidates --
    __syncthreads();
    float* rs_lds = reinterpret_cast<float*>(Ah);      // 128 f
    float* es_lds = rs_lds + 128;                      // 128 f
    float* rowmin_lds = es_lds + 128;                  // 128 f
    if (tid < 128) rs_lds[tid] = row_sq[row0 + tid];
    else if (tid < 256) es_lds[tid - 128] = emb_sq[col0 + tid - 128];
    __syncthreads();

    // C/D layout: row = (lane>>4)*4 + reg, col = lane&15 (per 16x16 frag)
    float rmin[16];
#pragma unroll
    for (int mf = 0; mf < 4; ++mf)
#pragma unroll
        for (int rg = 0; rg < 4; ++rg) {
            int rl = wr * 64 + mf * 16 + lg * 4 + rg;
            float rs = rs_lds[rl];
            float best = 3.4e38f;
#pragma unroll
            for (int nf = 0; nf < 4; ++nf) {
                int cl = wc * 64 + nf * 16 + li;
                float dv = (rs + es_lds[cl]) - 2.0f * acc[mf][nf][rg];
                dist[(size_t)(row0 + rl) * KCODES + col0 + cl] = dv;
                best = fminf(best, dv);
            }
            rmin[mf * 4 + rg] = best;
        }
#pragma unroll
    for (int m = 8; m >= 1; m >>= 1)
#pragma unroll
        for (int j = 0; j < 16; ++j) rmin[j] = fminf(rmin[j], __shfl_xor(rmin[j], m, 64));
    if (wc == 0 && li == 0) {
#pragma unroll
        for (int mf = 0; mf < 4; ++mf)
#pragma unroll
            for (int rg = 0; rg < 4; ++rg)
                rowmin_lds[wr * 64 + mf * 16 + lg * 4 + rg] = rmin[mf * 4 + rg];
    }
    __syncthreads();
    if (wc == 1 && li == 0) {
#pragma unroll
        for (int mf = 0; mf < 4; ++mf)
#pragma unroll
            for (int rg = 0; rg < 4; ++rg) {
                int rl = wr * 64 + mf * 16 + lg * 4 + rg;
                rowmin_lds[rl] = fminf(rowmin_lds[rl], rmin[mf * 4 + rg]);
            }
    }
    __syncthreads();
#pragma unroll
    for (int mf = 0; mf < 4; ++mf)
#pragma unroll
        for (int rg = 0; rg < 4; ++rg) {
            int rl = wr * 64 + mf * 16 + lg * 4 + rg;
            float thr = rowmin_lds[rl] + MARGIN;
            float rs = rs_lds[rl];
#pragma unroll
            for (int nf = 0; nf < 4; ++nf) {
                int cl = wc * 64 + nf * 16 + li;
                float dv = (rs + es_lds[cl]) - 2.0f * acc[mf][nf][rg];
                if (dv <= thr) {
                    int grow = row0 + rl;
                    u32 slot = atomicAdd(&cand_cnt[grow], 1u);
                    if (slot < MAXCAND) cand[(size_t)grow * MAXCAND + slot] = (u16)(col0 + cl);
                }
            }
        }
}

// ---------------- fallback: in-kernel-convert version (small ws) --------------
__global__ __launch_bounds__(256, 2) void dist_mfma_kernel(
    const float* __restrict__ A, const float* __restrict__ B,
    const float* __restrict__ row_sq, const float* __restrict__ emb_sq,
    float* __restrict__ dist, u32* __restrict__ cand_cnt, u16* __restrict__ cand) {
    __shared__ u16 Ah[128 * 40], Al[128 * 40], Bh[128 * 40], Bl[128 * 40];
    const int tid = threadIdx.x;
    const int lane = tid & 63, wid = tid >> 6;
    const int wr = wid >> 1, wc = wid & 1;
    const int li = lane & 15, lg = lane >> 4;
    const int row0 = blockIdx.y * 128, col0 = blockIdx.x * 128;
    const int rbase = tid >> 3, c4 = tid & 7;

    f32x4 acc[4][4];
#pragma unroll
    for (int mf = 0; mf < 4; ++mf)
#pragma unroll
        for (int nf = 0; nf < 4; ++nf) acc[mf][nf] = (f32x4)0.0f;

    float4 ra[4], rb[4];
#pragma unroll
    for (int i = 0; i < 4; ++i) {
        int r = rbase + i * 32;
        ra[i] = *reinterpret_cast<const float4*>(A + (size_t)(row0 + r) * DDIM + c4 * 4);
        rb[i] = *reinterpret_cast<const float4*>(B + (size_t)(col0 + r) * DDIM + c4 * 4);
    }

    for (int ks = 0; ks < 8; ++ks) {
        __syncthreads();
#pragma unroll
        for (int i = 0; i < 4; ++i) {
            int r = rbase + i * 32;
            float av[4] = {ra[i].x, ra[i].y, ra[i].z, ra[i].w};
            float bv[4] = {rb[i].x, rb[i].y, rb[i].z, rb[i].w};
            u32 ahb[4], alb[4], bhb[4], blb[4];
#pragma unroll
            for (int j = 0; j < 4; ++j) {
                ahb[j] = f2bf_bits(av[j]);
                alb[j] = f2bf_bits(av[j] - bf2f(ahb[j]));
                bhb[j] = f2bf_bits(bv[j]);
                blb[j] = f2bf_bits(bv[j] - bf2f(bhb[j]));
            }
            int o = r * 40 + c4 * 4;
            *reinterpret_cast<uint2*>(&Ah[o]) = make_uint2(ahb[0] | (ahb[1] << 16), ahb[2] | (ahb[3] << 16));
            *reinterpret_cast<uint2*>(&Al[o]) = make_uint2(alb[0] | (alb[1] << 16), alb[2] | (alb[3] << 16));
            *reinterpret_cast<uint2*>(&Bh[o]) = make_uint2(bhb[0] | (bhb[1] << 16), bhb[2] | (bhb[3] << 16));
            *reinterpret_cast<uint2*>(&Bl[o]) = make_uint2(blb[0] | (blb[1] << 16), blb[2] | (blb[3] << 16));
        }
        if (ks < 7) {
            int d0 = (ks + 1) * 32;
#pragma unroll
            for (int i = 0; i < 4; ++i) {
                int r = rbase + i * 32;
                ra[i] = *reinterpret_cast<const float4*>(A + (size_t)(row0 + r) * DDIM + d0 + c4 * 4);
                rb[i] = *reinterpret_cast<const float4*>(B + (size_t)(col0 + r) * DDIM + d0 + c4 * 4);
            }
        }
        __syncthreads();
        bf16x8 fah[4], fal[4], fbh[4], fbl[4];
        int k0 = lg * 8;
#pragma unroll
        for (int mf = 0; mf < 4; ++mf) {
            int r = wr * 64 + mf * 16 + li;
            fah[mf] = *reinterpret_cast<const bf16x8*>(&Ah[r * 40 + k0]);
            fal[mf] = *reinterpret_cast<const bf16x8*>(&Al[r * 40 + k0]);
        }
#pragma unroll
        for (int nf = 0; nf < 4; ++nf) {
            int c = wc * 64 + nf * 16 + li;
            fbh[nf] = *reinterpret_cast<const bf16x8*>(&Bh[c * 40 + k0]);
            fbl[nf] = *reinterpret_cast<const bf16x8*>(&Bl[c * 40 + k0]);
        }
#pragma unroll
        for (int mf = 0; mf < 4; ++mf)
#pragma unroll
            for (int nf = 0; nf < 4; ++nf) {
                acc[mf][nf] = __builtin_amdgcn_mfma_f32_16x16x32_bf16(fah[mf], fbh[nf], acc[mf][nf], 0, 0, 0);
                acc[mf][nf] = __builtin_amdgcn_mfma_f32_16x16x32_bf16(fah[mf], fbl[nf], acc[mf][nf], 0, 0, 0);
                acc[mf][nf] = __builtin_amdgcn_mfma_f32_16x16x32_bf16(fal[mf], fbh[nf], acc[mf][nf], 0, 0, 0);
            }
    }

    __syncthreads();
    float* rs_lds = reinterpret_cast<float*>(Ah);
    float* es_lds = rs_lds + 128;
    float* rowmin_lds = es_lds + 128;
    if (tid < 128) rs_lds[tid] = row_sq[row0 + tid];
    else if (tid < 256) es_lds[tid - 128] = emb_sq[col0 + tid - 128];
    __syncthreads();

    float rmin[16];
#pragma unroll
    for (int mf = 0; mf < 4; ++mf)
#pragma unroll
        for (int rg = 0; rg < 4; ++rg) {
            int rl = wr * 64 + mf * 16 + lg * 4 + rg;
            float rs = rs_lds[rl];
            float best = 3.4e38f;
#pragma unroll
            for (int nf = 0; nf < 4; ++nf) {
                int cl = wc * 64 + nf * 16 + li;
                float dv = (rs + es_lds[cl]) - 2.0f * acc[mf][nf][rg];
                dist[(size_t)(row0 + rl) * KCODES + col0 + cl] = dv;
                best = fminf(best, dv);
            }
            rmin[mf * 4 + rg] = best;
        }
#pragma unroll
    for (int m = 8; m >= 1; m >>= 1)
#pragma unroll
        for (int j = 0; j < 16; ++j) rmin[j] = fminf(rmin[j], __shfl_xor(rmin[j], m, 64));
    if (wc == 0 && li == 0) {
#pragma unroll
        for (int mf = 0; mf < 4; ++mf)
#pragma unroll
            for (int rg = 0; rg < 4; ++rg)
                rowmin_lds[wr * 64 + mf * 16 + lg * 4 + rg] = rmin[mf * 4 + rg];
    }
    __syncthreads();
    if (wc == 1 && li == 0) {
#pragma unroll
        for (int mf = 0; mf < 4; ++mf)
#pragma unroll
            for (int rg = 0; rg < 4; ++rg) {
                int rl = wr * 64 + mf * 16 + lg * 4 + rg;
                rowmin_lds[rl] = fminf(rowmin_lds[rl], rmin[mf * 4 + rg]);
            }
    }
    __syncthreads();
#pragma unroll
    for (int mf = 0; mf < 4; ++mf)
#pragma unroll
        for (int rg = 0; rg < 4; ++rg) {
            int rl = wr * 64 + mf * 16 + lg * 4 + rg;
            float thr = rowmin_lds[rl] + MARGIN;
            float rs = rs_lds[rl];
#pragma unroll
            for (int nf = 0; nf < 4; ++nf) {
                int cl = wc * 64 + nf * 16 + li;
                float dv = (rs + es_lds[cl]) - 2.0f * acc[mf][nf][rg];
                if (dv <= thr) {
                    int grow = row0 + rl;
                    u32 slot = atomicAdd(&cand_cnt[grow], 1u);
                    if (slot < MAXCAND) cand[(size_t)grow * MAXCAND + slot] = (u16)(col0 + cl);
                }
            }
        }
}

// ------- refine: bit-exact fp32 serial-FMA compare; 4 rows/wave, 8-deep MLP ---
// Wave = 4 rows x 16 candidate slots (64 distinct chains). e-row loads run in
// an 8-deep named-register software pipeline (8 outstanding VMEM per lane).
// FMA chain order identical to the plain fp32 GEMM -> same tie-bins as np ref.
__global__ __launch_bounds__(256) void refine_gather_kernel(
    const float* __restrict__ lat, const float* __restrict__ emb,
    const float* __restrict__ row_sq, const float* __restrict__ emb_sq,
    const u32* __restrict__ cand_cnt, const u16* __restrict__ cand,
    float* __restrict__ qout, float* __restrict__ indout,
    u32* __restrict__ hist, float* __restrict__ loss_part) {
    __shared__ __align__(16) float xs[4][4][260];  // [wave][rowInWave][256+pad]
    __shared__ int bestc_l[16];
    __shared__ float lred[4];
    const int w = threadIdx.x >> 6, lane = threadIdx.x & 63;
    const int rw = lane >> 4, slot = lane & 15;
    const int row0 = blockIdx.x * 16;

    // stage this wave's 4 x-rows into LDS (also reused by gather phase)
#pragma unroll
    for (int rr = 0; rr < 4; ++rr) {
        int row = row0 + w * 4 + rr;
        float4 xv = *reinterpret_cast<const float4*>(lat + (size_t)row * DDIM + lane * 4);
        *reinterpret_cast<float4*>(&xs[w][rr][lane * 4]) = xv;
    }
    __syncthreads();

    const int row = row0 + w * 4 + rw;
    int cnt = (int)cand_cnt[row];
    if (cnt > MAXCAND) cnt = MAXCAND;
    int sl = (slot < cnt) ? slot : 0;   // cnt >= 1 always (block-min recorded)
    int c = cand[(size_t)row * MAXCAND + sl];

    const float* erow = emb + (size_t)c * DDIM;
    float4 e0 = *reinterpret_cast<const float4*>(erow + 0);
    float4 e1 = *reinterpret_cast<const float4*>(erow + 4);
    float4 e2 = *reinterpret_cast<const float4*>(erow + 8);
    float4 e3 = *reinterpret_cast<const float4*>(erow + 12);
    float4 e4 = *reinterpret_cast<const float4*>(erow + 16);
    float4 e5 = *reinterpret_cast<const float4*>(erow + 20);
    float4 e6 = *reinterpret_cast<const float4*>(erow + 24);
    float4 e7 = *reinterpret_cast<const float4*>(erow + 28);
    float acc = 0.0f;
#define STEP(PF, K) { \
        float4 xq = *reinterpret_cast<const float4*>(&xs[w][rw][(K) * 4]); \
        acc = __builtin_fmaf(xq.x, PF.x, acc); \
        acc = __builtin_fmaf(xq.y, PF.y, acc); \
        acc = __builtin_fmaf(xq.z, PF.z, acc); \
        acc = __builtin_fmaf(xq.w, PF.w, acc); \
        if ((K) + 8 < 64) PF = *reinterpret_cast<const float4*>(erow + ((K) + 8) * 4); }
#define GROUP(G) STEP(e0, (G)*8+0) STEP(e1, (G)*8+1) STEP(e2, (G)*8+2) STEP(e3, (G)*8+3) \
                 STEP(e4, (G)*8+4) STEP(e5, (G)*8+5) STEP(e6, (G)*8+6) STEP(e7, (G)*8+7)
    GROUP(0) GROUP(1) GROUP(2) GROUP(3) GROUP(4) GROUP(5) GROUP(6) GROUP(7)
#undef GROUP
#undef STEP
    float t = row_sq[row] + emb_sq[c];
    float dv = __builtin_fmaf(-2.0f, acc, t);   // == t - 2*acc exactly (x2 exact)

    // lexicographic (dv, index) min over the 16 slots of this row
#pragma unroll
    for (int m = 8; m >= 1; m >>= 1) {
        float od = __shfl_xor(dv, m, 64);
        int oc = __shfl_xor(c, m, 64);
        if (od < dv || (od == dv && oc < c)) { dv = od; c = oc; }
    }
    if (slot == 0) {
        bestc_l[w * 4 + rw] = c;
        indout[row] = (float)c;
        atomicAdd(&hist[c], 1u);
    }
    __syncthreads();

    // gather phase: pass p -> wave w handles local row p*4+w == xs[p][w]
    float ssum = 0.0f;
#pragma unroll
    for (int p = 0; p < 4; ++p) {
        int rl = p * 4 + w;
        int grow = row0 + rl;
        int bc = bestc_l[rl];
        float4 xv = *reinterpret_cast<const float4*>(&xs[p][w][lane * 4]);
        float4 ev = *reinterpret_cast<const float4*>(emb + (size_t)bc * DDIM + lane * 4);
        float dx = ev.x - xv.x, dy = ev.y - xv.y, dz = ev.z - xv.z, dw = ev.w - xv.w;
        float4 q = make_float4(xv.x + dx, xv.y + dy, xv.z + dz, xv.w + dw);
        *reinterpret_cast<float4*>(qout + (size_t)grow * DDIM + lane * 4) = q;
        float s = dx * dx + dy * dy + dz * dz + dw * dw;
#pragma unroll
        for (int m = 32; m >= 1; m >>= 1) s += __shfl_xor(s, m, 64);
        ssum += s;
    }
    if (lane == 0) lred[w] = ssum;
    __syncthreads();
    if (threadIdx.x == 0)
        loss_part[blockIdx.x] = (lred[0] + lred[1]) + (lred[2] + lred[3]);
}

// ---------------- scalars: vq_loss (reduce partials), perplexity ---------------
__global__ __launch_bounds__(1024) void scalar_kernel(
    const u32* __restrict__ hist, const float* __restrict__ loss_part,
    float* __restrict__ out_loss, float* __restrict__ out_perp) {
    __shared__ double lred[16];
    __shared__ float ered[16];
    int t = threadIdx.x;
    double ls = 0.0;
#pragma unroll
    for (int i = 0; i < RG_BLOCKS / 1024; ++i)
        ls += (double)loss_part[t + i * 1024];
    float p = (float)hist[t] / 65536.0f;
    float es = p * logf(p + 1e-10f);
#pragma unroll
    for (int m = 32; m >= 1; m >>= 1) {
        ls += __shfl_xor(ls, m, 64);
        es += __shfl_xor(es, m, 64);
    }
    if ((t & 63) == 0) { lred[t >> 6] = ls; ered[t >> 6] = es; }
    __syncthreads();
    if (t < 64) {
        double lv = (t < 16) ? lred[t] : 0.0;
        float ev = (t < 16) ? ered[t] : 0.0f;
#pragma unroll
        for (int m = 32; m >= 1; m >>= 1) {
            lv += __shfl_xor(lv, m, 64);
            ev += __shfl_xor(ev, m, 64);
        }
        if (t == 0) {
            *out_perp = expf(-ev);
            double ml = lv / (double)((size_t)NROWS * DDIM);
            *out_loss = (float)(ml * 0.25 + ml);  // beta*commit + delta*embed (equal)
        }
    }
}

extern "C" void kernel_launch(void* const* d_in, const int* in_sizes, int n_in,
                              void* d_out, int out_size, void* d_ws, size_t ws_size,
                              hipStream_t stream) {
    const float* lat = (const float*)d_in[0];
    const float* emb = (const float*)d_in[1];
    float* out = (float*)d_out;
    char* ws = (char*)d_ws;

    u32* cand_cnt = (u32*)ws;                          // 262144 B
    u16* cand = (u16*)(ws + 262144);                   // 2097152 B
    float* row_sq = (float*)(ws + 2359296);            // 262144 B
    float* emb_sq = (float*)(ws + 2621440);            // 4096 B
    u32* hist = (u32*)(ws + 2625536);                  // 4096 B
    float* loss_part = (float*)(ws + 2629632);         // 65536 B
    u16* Ahg = (u16*)(ws + 2695168);                   // 33554432 B
    u16* Alg = (u16*)(ws + 36249600);                  // 33554432 B
    u16* Bhg = (u16*)(ws + 69804032);                  // 524288 B
    u16* Blg = (u16*)(ws + 70328320);                  // 524288 B
    const size_t WS_NEED = 70852608;

    init_kernel<<<256, 256, 0, stream>>>(cand_cnt, hist);
    sqnorm_kernel<<<(NROWS + KCODES) / 4, 256, 0, stream>>>(lat, emb, row_sq, emb_sq);
    dim3 grid(KCODES / 128, NROWS / 128);
    if (ws_size >= WS_NEED) {
        convert_kernel<<<2048, 256, 0, stream>>>(lat, emb, Ahg, Alg, Bhg, Blg);
        dist_mfma2_kernel<<<grid, 256, 0, stream>>>(Ahg, Alg, Bhg, Blg, row_sq, emb_sq,
                                                    out + DIST_OFF, cand_cnt, cand);
    } else {
        dist_mfma_kernel<<<grid, 256, 0, stream>>>(lat, emb, row_sq, emb_sq,
                                                   out + DIST_OFF, cand_cnt, cand);
    }
    refine_gather_kernel<<<RG_BLOCKS, 256, 0, stream>>>(lat, emb, row_sq, emb_sq,
                                                        cand_cnt, cand,
                                                        out + Q_OFF, out + IND_OFF,
                                                        hist, loss_part);
    scalar_kernel<<<1, 1024, 0, stream>>>(hist, loss_part,
                                          out + LOSS_OFF, out + PERP_OFF);
}

// Round 7
// 347.015 us; speedup vs baseline: 1.6828x; 1.1082x over previous
//
#include <hip/hip_runtime.h>

#define NROWS 65536
#define KCODES 1024
#define DDIM 256

// output offsets in floats (concat of reference return tuple)
#define Q_OFF    0
#define LOSS_OFF 16777216
#define PERP_OFF 16777217
#define IND_OFF  16777218
#define DIST_OFF 16842754

#define MARGIN  4e-4f
#define MAXCAND 16
#define RG_BLOCKS (NROWS / 16)   // 4096 blocks, 16 rows each

typedef unsigned long long u64;
typedef unsigned int u32;
typedef unsigned short u16;
typedef __attribute__((ext_vector_type(8))) short bf16x8;
typedef __attribute__((ext_vector_type(4))) float f32x4;

// RNE float->bf16 bits (no NaN handling; inputs are tame)
__device__ inline u32 f2bf_bits(float f) {
    u32 u = __float_as_uint(f);
    return (u + 0x7fffu + ((u >> 16) & 1u)) >> 16;
}
__device__ inline float bf2f(u32 bits) { return __uint_as_float(bits << 16); }

__device__ inline void gload16(const void* g, void* l) {
    __builtin_amdgcn_global_load_lds(
        (const __attribute__((address_space(1))) unsigned int*)g,
        (__attribute__((address_space(3))) unsigned int*)l, 16, 0, 0);
}

// ---------------- init workspace ----------------------------------------------
__global__ __launch_bounds__(256) void init_kernel(u32* __restrict__ cand_cnt,
                                                   u32* __restrict__ hist) {
    int i = blockIdx.x * 256 + threadIdx.x;
    if (i < NROWS) cand_cnt[i] = 0u;
    if (i < KCODES) hist[i] = 0u;
}

// ---------------- squared norms (unchanged order -> stable rs/es bits) --------
__global__ __launch_bounds__(256) void sqnorm_kernel(
    const float* __restrict__ lat, const float* __restrict__ emb,
    float* __restrict__ row_sq, float* __restrict__ emb_sq) {
    int gwave = (blockIdx.x * 256 + threadIdx.x) >> 6;
    int lane = threadIdx.x & 63;
    if (gwave >= NROWS + KCODES) return;
    const float* src = (gwave < NROWS) ? lat + (size_t)gwave * DDIM
                                       : emb + (size_t)(gwave - NROWS) * DDIM;
    float4 v = *reinterpret_cast<const float4*>(src + lane * 4);
    float s = v.x * v.x + v.y * v.y + v.z * v.z + v.w * v.w;
#pragma unroll
    for (int m = 32; m >= 1; m >>= 1) s += __shfl_xor(s, m, 64);
    if (lane == 0) {
        if (gwave < NROWS) row_sq[gwave] = s;
        else emb_sq[gwave - NROWS] = s;
    }
}

// -------- fp32 -> (bf16 hi|lo) split into TILED + CHUNK-SWIZZLED layout -------
// Apre[tile][ks][r 0..127][chunk 0..7], chunk = 16B; logical octet c (0..3 hi,
// 4..7 lo) stored at chunk c ^ (r&7). Global layout == LDS image per K-step,
// so dist staging is linear global_load_lds and reads apply the XOR.
__global__ __launch_bounds__(256) void convert_kernel(
    const float* __restrict__ lat, const float* __restrict__ emb,
    u16* __restrict__ Apre, u16* __restrict__ Bpre) {
    const int NA_IT = NROWS * 32;   // (row, ks, c) items
    const int NB_IT = KCODES * 32;
    int g = blockIdx.x * 256 + threadIdx.x;
    if (g >= NA_IT + NB_IT) return;
    const float* src;
    uint4* dst;
    int it;
    if (g < NA_IT) { src = lat; dst = (uint4*)Apre; it = g; }
    else           { src = emb; dst = (uint4*)Bpre; it = g - NA_IT; }
    int c = it & 3, ks = (it >> 2) & 7, rg = it >> 5;
    const float* s = src + (size_t)rg * DDIM + ks * 32 + c * 8;
    float4 v0 = *reinterpret_cast<const float4*>(s);
    float4 v1 = *reinterpret_cast<const float4*>(s + 4);
    u32 h0 = f2bf_bits(v0.x), h1 = f2bf_bits(v0.y), h2 = f2bf_bits(v0.z), h3 = f2bf_bits(v0.w);
    u32 h4 = f2bf_bits(v1.x), h5 = f2bf_bits(v1.y), h6 = f2bf_bits(v1.z), h7 = f2bf_bits(v1.w);
    u32 l0 = f2bf_bits(v0.x - bf2f(h0)), l1 = f2bf_bits(v0.y - bf2f(h1));
    u32 l2 = f2bf_bits(v0.z - bf2f(h2)), l3 = f2bf_bits(v0.w - bf2f(h3));
    u32 l4 = f2bf_bits(v1.x - bf2f(h4)), l5 = f2bf_bits(v1.y - bf2f(h5));
    u32 l6 = f2bf_bits(v1.z - bf2f(h6)), l7 = f2bf_bits(v1.w - bf2f(h7));
    uint4 hq = make_uint4(h0 | (h1 << 16), h2 | (h3 << 16), h4 | (h5 << 16), h6 | (h7 << 16));
    uint4 lq = make_uint4(l0 | (l1 << 16), l2 | (l3 << 16), l4 | (l5 << 16), l6 | (l7 << 16));
    int r = rg & 127, tile = rg >> 7;
    size_t b16 = ((size_t)(tile * 8 + ks) * 128 + r) * 8;   // uint4 units
    dst[b16 + (c ^ (r & 7))] = hq;
    dst[b16 + ((c + 4) ^ (r & 7))] = lq;
}

// ---------------- dist: m97-style gload_lds + swizzled reads ------------------
// 128x128 tile, BK=32, 4 waves, single 32KB LDS buffer. Bit-identical dv vs
// prior rounds (same split, same fragment contents, same MFMA order).
__global__ __launch_bounds__(256, 3) void dist_mfma3_kernel(
    const u16* __restrict__ Apre, const u16* __restrict__ Bpre,
    const float* __restrict__ row_sq, const float* __restrict__ emb_sq,
    float* __restrict__ dist, u32* __restrict__ cand_cnt, u16* __restrict__ cand) {
    __shared__ u16 Ash[128 * 64];   // 16KB
    __shared__ u16 Bsh[128 * 64];   // 16KB
    const int tid = threadIdx.x;
    const int lane = tid & 63, wid = tid >> 6;
    const int wr = wid >> 1, wc = wid & 1;       // wave quadrant (64x64)
    const int li = lane & 15, lg = lane >> 4;
    // XCD-aware swizzle: each XCD gets contiguous row-tiles (A-panel L2 reuse)
    const int swzb = (blockIdx.x & 7) * 512 + (blockIdx.x >> 3);
    const int rt = swzb >> 3, ct = swzb & 7;
    const int row0 = rt * 128, col0 = ct * 128;

    const char* Ab = (const char*)Apre + (size_t)rt * (8 * 16384);
    const char* Bb = (const char*)Bpre + (size_t)ct * (8 * 16384);
    char* AshB = (char*)Ash;
    char* BshB = (char*)Bsh;
    const int so = wid * 4096 + lane * 16;   // per-lane global offset
    const int dso = wid * 4096;              // wave-uniform LDS offset

    f32x4 acc[4][4];
#pragma unroll
    for (int mf = 0; mf < 4; ++mf)
#pragma unroll
        for (int nf = 0; nf < 4; ++nf) acc[mf][nf] = (f32x4)0.0f;

    for (int ks = 0; ks < 8; ++ks) {
        __syncthreads();  // previous iter's LDS reads done
        const char* Asrc = Ab + ks * 16384;
        const char* Bsrc = Bb + ks * 16384;
#pragma unroll
        for (int i = 0; i < 4; ++i) {
            gload16(Asrc + so + i * 1024, AshB + dso + i * 1024);
            gload16(Bsrc + so + i * 1024, BshB + dso + i * 1024);
        }
        __syncthreads();  // vmcnt(0) drain: staged data visible
        bf16x8 fah[4], fal[4], fbh[4], fbl[4];
#pragma unroll
        for (int mf = 0; mf < 4; ++mf) {
            int r = wr * 64 + mf * 16 + li;
            int o = r * 128 + ((lg ^ (r & 7)) << 4);
            fah[mf] = *reinterpret_cast<const bf16x8*>(AshB + o);
            fal[mf] = *reinterpret_cast<const bf16x8*>(AshB + (o ^ 64));
        }
#pragma unroll
        for (int nf = 0; nf < 4; ++nf) {
            int cc = wc * 64 + nf * 16 + li;
            int o = cc * 128 + ((lg ^ (cc & 7)) << 4);
            fbh[nf] = *reinterpret_cast<const bf16x8*>(BshB + o);
            fbl[nf] = *reinterpret_cast<const bf16x8*>(BshB + (o ^ 64));
        }
#pragma unroll
        for (int mf = 0; mf < 4; ++mf)
#pragma unroll
            for (int nf = 0; nf < 4; ++nf) {
                acc[mf][nf] = __builtin_amdgcn_mfma_f32_16x16x32_bf16(fah[mf], fbh[nf], acc[mf][nf], 0, 0, 0);
                acc[mf][nf] = __builtin_amdgcn_mfma_f32_16x16x32_bf16(fah[mf], fbl[nf], acc[mf][nf], 0, 0, 0);
                acc[mf][nf] = __builtin_amdgcn_mfma_f32_16x16x32_bf16(fal[mf], fbh[nf], acc[mf][nf], 0, 0, 0);
            }
    }

    // ---------------- epilogue: dist write + block-local row-min + candidates --
    __syncthreads();
    float* rs_lds = reinterpret_cast<float*>(Ash);     // 128 f
    float* es_lds = rs_lds + 128;                      // 128 f
    float* rowmin_lds = es_lds + 128;                  // 128 f
    if (tid < 128) rs_lds[tid] = row_sq[row0 + tid];
    else if (tid < 256) es_lds[tid - 128] = emb_sq[col0 + tid - 128];
    __syncthreads();

    // C/D layout: row = (lane>>4)*4 + reg, col = lane&15 (per 16x16 frag)
    float rmin[16];
#pragma unroll
    for (int mf = 0; mf < 4; ++mf)
#pragma unroll
        for (int rg = 0; rg < 4; ++rg) {
            int rl = wr * 64 + mf * 16 + lg * 4 + rg;
            float rs = rs_lds[rl];
            float best = 3.4e38f;
#pragma unroll
            for (int nf = 0; nf < 4; ++nf) {
                int cl = wc * 64 + nf * 16 + li;
                float dv = (rs + es_lds[cl]) - 2.0f * acc[mf][nf][rg];
                dist[(size_t)(row0 + rl) * KCODES + col0 + cl] = dv;
                best = fminf(best, dv);
            }
            rmin[mf * 4 + rg] = best;
        }
#pragma unroll
    for (int m = 8; m >= 1; m >>= 1)
#pragma unroll
        for (int j = 0; j < 16; ++j) rmin[j] = fminf(rmin[j], __shfl_xor(rmin[j], m, 64));
    if (wc == 0 && li == 0) {
#pragma unroll
        for (int mf = 0; mf < 4; ++mf)
#pragma unroll
            for (int rg = 0; rg < 4; ++rg)
                rowmin_lds[wr * 64 + mf * 16 + lg * 4 + rg] = rmin[mf * 4 + rg];
    }
    __syncthreads();
    if (wc == 1 && li == 0) {
#pragma unroll
        for (int mf = 0; mf < 4; ++mf)
#pragma unroll
            for (int rg = 0; rg < 4; ++rg) {
                int rl = wr * 64 + mf * 16 + lg * 4 + rg;
                rowmin_lds[rl] = fminf(rowmin_lds[rl], rmin[mf * 4 + rg]);
            }
    }
    __syncthreads();
#pragma unroll
    for (int mf = 0; mf < 4; ++mf)
#pragma unroll
        for (int rg = 0; rg < 4; ++rg) {
            int rl = wr * 64 + mf * 16 + lg * 4 + rg;
            float thr = rowmin_lds[rl] + MARGIN;
            float rs = rs_lds[rl];
#pragma unroll
            for (int nf = 0; nf < 4; ++nf) {
                int cl = wc * 64 + nf * 16 + li;
                float dv = (rs + es_lds[cl]) - 2.0f * acc[mf][nf][rg];
                if (dv <= thr) {
                    int grow = row0 + rl;
                    u32 slot = atomicAdd(&cand_cnt[grow], 1u);
                    if (slot < MAXCAND) cand[(size_t)grow * MAXCAND + slot] = (u16)(col0 + cl);
                }
            }
        }
}

// ---------------- fallback: in-kernel-convert version (small ws) --------------
__global__ __launch_bounds__(256, 2) void dist_mfma_kernel(
    const float* __restrict__ A, const float* __restrict__ B,
    const float* __restrict__ row_sq, const float* __restrict__ emb_sq,
    float* __restrict__ dist, u32* __restrict__ cand_cnt, u16* __restrict__ cand) {
    __shared__ u16 Ah[128 * 40], Al[128 * 40], Bh[128 * 40], Bl[128 * 40];
    const int tid = threadIdx.x;
    const int lane = tid & 63, wid = tid >> 6;
    const int wr = wid >> 1, wc = wid & 1;
    const int li = lane & 15, lg = lane >> 4;
    const int row0 = blockIdx.y * 128, col0 = blockIdx.x * 128;
    const int rbase = tid >> 3, c4 = tid & 7;

    f32x4 acc[4][4];
#pragma unroll
    for (int mf = 0; mf < 4; ++mf)
#pragma unroll
        for (int nf = 0; nf < 4; ++nf) acc[mf][nf] = (f32x4)0.0f;

    float4 ra[4], rb[4];
#pragma unroll
    for (int i = 0; i < 4; ++i) {
        int r = rbase + i * 32;
        ra[i] = *reinterpret_cast<const float4*>(A + (size_t)(row0 + r) * DDIM + c4 * 4);
        rb[i] = *reinterpret_cast<const float4*>(B + (size_t)(col0 + r) * DDIM + c4 * 4);
    }

    for (int ks = 0; ks < 8; ++ks) {
        __syncthreads();
#pragma unroll
        for (int i = 0; i < 4; ++i) {
            int r = rbase + i * 32;
            float av[4] = {ra[i].x, ra[i].y, ra[i].z, ra[i].w};
            float bv[4] = {rb[i].x, rb[i].y, rb[i].z, rb[i].w};
            u32 ahb[4], alb[4], bhb[4], blb[4];
#pragma unroll
            for (int j = 0; j < 4; ++j) {
                ahb[j] = f2bf_bits(av[j]);
                alb[j] = f2bf_bits(av[j] - bf2f(ahb[j]));
                bhb[j] = f2bf_bits(bv[j]);
                blb[j] = f2bf_bits(bv[j] - bf2f(bhb[j]));
            }
            int o = r * 40 + c4 * 4;
            *reinterpret_cast<uint2*>(&Ah[o]) = make_uint2(ahb[0] | (ahb[1] << 16), ahb[2] | (ahb[3] << 16));
            *reinterpret_cast<uint2*>(&Al[o]) = make_uint2(alb[0] | (alb[1] << 16), alb[2] | (alb[3] << 16));
            *reinterpret_cast<uint2*>(&Bh[o]) = make_uint2(bhb[0] | (bhb[1] << 16), bhb[2] | (bhb[3] << 16));
            *reinterpret_cast<uint2*>(&Bl[o]) = make_uint2(blb[0] | (blb[1] << 16), blb[2] | (blb[3] << 16));
        }
        if (ks < 7) {
            int d0 = (ks + 1) * 32;
#pragma unroll
            for (int i = 0; i < 4; ++i) {
                int r = rbase + i * 32;
                ra[i] = *reinterpret_cast<const float4*>(A + (size_t)(row0 + r) * DDIM + d0 + c4 * 4);
                rb[i] = *reinterpret_cast<const float4*>(B + (size_t)(col0 + r) * DDIM + d0 + c4 * 4);
            }
        }
        __syncthreads();
        bf16x8 fah[4], fal[4], fbh[4], fbl[4];
        int k0 = lg * 8;
#pragma unroll
        for (int mf = 0; mf < 4; ++mf) {
            int r = wr * 64 + mf * 16 + li;
            fah[mf] = *reinterpret_cast<const bf16x8*>(&Ah[r * 40 + k0]);
            fal[mf] = *reinterpret_cast<const bf16x8*>(&Al[r * 40 + k0]);
        }
#pragma unroll
        for (int nf = 0; nf < 4; ++nf) {
            int c = wc * 64 + nf * 16 + li;
            fbh[nf] = *reinterpret_cast<const bf16x8*>(&Bh[c * 40 + k0]);
            fbl[nf] = *reinterpret_cast<const bf16x8*>(&Bl[c * 40 + k0]);
        }
#pragma unroll
        for (int mf = 0; mf < 4; ++mf)
#pragma unroll
            for (int nf = 0; nf < 4; ++nf) {
                acc[mf][nf] = __builtin_amdgcn_mfma_f32_16x16x32_bf16(fah[mf], fbh[nf], acc[mf][nf], 0, 0, 0);
                acc[mf][nf] = __builtin_amdgcn_mfma_f32_16x16x32_bf16(fah[mf], fbl[nf], acc[mf][nf], 0, 0, 0);
                acc[mf][nf] = __builtin_amdgcn_mfma_f32_16x16x32_bf16(fal[mf], fbh[nf], acc[mf][nf], 0, 0, 0);
            }
    }

    __syncthreads();
    float* rs_lds = reinterpret_cast<float*>(Ah);
    float* es_lds = rs_lds + 128;
    float* rowmin_lds = es_lds + 128;
    if (tid < 128) rs_lds[tid] = row_sq[row0 + tid];
    else if (tid < 256) es_lds[tid - 128] = emb_sq[col0 + tid - 128];
    __syncthreads();

    float rmin[16];
#pragma unroll
    for (int mf = 0; mf < 4; ++mf)
#pragma unroll
        for (int rg = 0; rg < 4; ++rg) {
            int rl = wr * 64 + mf * 16 + lg * 4 + rg;
            float rs = rs_lds[rl];
            float best = 3.4e38f;
#pragma unroll
            for (int nf = 0; nf < 4; ++nf) {
                int cl = wc * 64 + nf * 16 + li;
                float dv = (rs + es_lds[cl]) - 2.0f * acc[mf][nf][rg];
                dist[(size_t)(row0 + rl) * KCODES + col0 + cl] = dv;
                best = fminf(best, dv);
            }
            rmin[mf * 4 + rg] = best;
        }
#pragma unroll
    for (int m = 8; m >= 1; m >>= 1)
#pragma unroll
        for (int j = 0; j < 16; ++j) rmin[j] = fminf(rmin[j], __shfl_xor(rmin[j], m, 64));
    if (wc == 0 && li == 0) {
#pragma unroll
        for (int mf = 0; mf < 4; ++mf)
#pragma unroll
            for (int rg = 0; rg < 4; ++rg)
                rowmin_lds[wr * 64 + mf * 16 + lg * 4 + rg] = rmin[mf * 4 + rg];
    }
    __syncthreads();
    if (wc == 1 && li == 0) {
#pragma unroll
        for (int mf = 0; mf < 4; ++mf)
#pragma unroll
            for (int rg = 0; rg < 4; ++rg) {
                int rl = wr * 64 + mf * 16 + lg * 4 + rg;
                rowmin_lds[rl] = fminf(rowmin_lds[rl], rmin[mf * 4 + rg]);
            }
    }
    __syncthreads();
#pragma unroll
    for (int mf = 0; mf < 4; ++mf)
#pragma unroll
        for (int rg = 0; rg < 4; ++rg) {
            int rl = wr * 64 + mf * 16 + lg * 4 + rg;
            float thr = rowmin_lds[rl] + MARGIN;
            float rs = rs_lds[rl];
#pragma unroll
            for (int nf = 0; nf < 4; ++nf) {
                int cl = wc * 64 + nf * 16 + li;
                float dv = (rs + es_lds[cl]) - 2.0f * acc[mf][nf][rg];
                if (dv <= thr) {
                    int grow = row0 + rl;
                    u32 slot = atomicAdd(&cand_cnt[grow], 1u);
                    if (slot < MAXCAND) cand[(size_t)grow * MAXCAND + slot] = (u16)(col0 + cl);
                }
            }
        }
}

// ------- refine: bit-exact fp32 serial-FMA compare; 4 rows/wave, 8-deep MLP ---
__global__ __launch_bounds__(256) void refine_gather_kernel(
    const float* __restrict__ lat, const float* __restrict__ emb,
    const float* __restrict__ row_sq, const float* __restrict__ emb_sq,
    const u32* __restrict__ cand_cnt, const u16* __restrict__ cand,
    float* __restrict__ qout, float* __restrict__ indout,
    u32* __restrict__ hist, float* __restrict__ loss_part) {
    __shared__ __align__(16) float xs[4][4][260];  // [wave][rowInWave][256+pad]
    __shared__ int bestc_l[16];
    __shared__ float lred[4];
    const int w = threadIdx.x >> 6, lane = threadIdx.x & 63;
    const int rw = lane >> 4, slot = lane & 15;
    const int row0 = blockIdx.x * 16;

#pragma unroll
    for (int rr = 0; rr < 4; ++rr) {
        int row = row0 + w * 4 + rr;
        float4 xv = *reinterpret_cast<const float4*>(lat + (size_t)row * DDIM + lane * 4);
        *reinterpret_cast<float4*>(&xs[w][rr][lane * 4]) = xv;
    }
    __syncthreads();

    const int row = row0 + w * 4 + rw;
    int cnt = (int)cand_cnt[row];
    if (cnt > MAXCAND) cnt = MAXCAND;
    int sl = (slot < cnt) ? slot : 0;   // cnt >= 1 always (block-min recorded)
    int c = cand[(size_t)row * MAXCAND + sl];

    const float* erow = emb + (size_t)c * DDIM;
    float4 e0 = *reinterpret_cast<const float4*>(erow + 0);
    float4 e1 = *reinterpret_cast<const float4*>(erow + 4);
    float4 e2 = *reinterpret_cast<const float4*>(erow + 8);
    float4 e3 = *reinterpret_cast<const float4*>(erow + 12);
    float4 e4 = *reinterpret_cast<const float4*>(erow + 16);
    float4 e5 = *reinterpret_cast<const float4*>(erow + 20);
    float4 e6 = *reinterpret_cast<const float4*>(erow + 24);
    float4 e7 = *reinterpret_cast<const float4*>(erow + 28);
    float acc = 0.0f;
#define STEP(PF, K) { \
        float4 xq = *reinterpret_cast<const float4*>(&xs[w][rw][(K) * 4]); \
        acc = __builtin_fmaf(xq.x, PF.x, acc); \
        acc = __builtin_fmaf(xq.y, PF.y, acc); \
        acc = __builtin_fmaf(xq.z, PF.z, acc); \
        acc = __builtin_fmaf(xq.w, PF.w, acc); \
        if ((K) + 8 < 64) PF = *reinterpret_cast<const float4*>(erow + ((K) + 8) * 4); }
#define GROUP(G) STEP(e0, (G)*8+0) STEP(e1, (G)*8+1) STEP(e2, (G)*8+2) STEP(e3, (G)*8+3) \
                 STEP(e4, (G)*8+4) STEP(e5, (G)*8+5) STEP(e6, (G)*8+6) STEP(e7, (G)*8+7)
    GROUP(0) GROUP(1) GROUP(2) GROUP(3) GROUP(4) GROUP(5) GROUP(6) GROUP(7)
#undef GROUP
#undef STEP
    float t = row_sq[row] + emb_sq[c];
    float dv = __builtin_fmaf(-2.0f, acc, t);   // == t - 2*acc exactly (x2 exact)

#pragma unroll
    for (int m = 8; m >= 1; m >>= 1) {
        float od = __shfl_xor(dv, m, 64);
        int oc = __shfl_xor(c, m, 64);
        if (od < dv || (od == dv && oc < c)) { dv = od; c = oc; }
    }
    if (slot == 0) {
        bestc_l[w * 4 + rw] = c;
        indout[row] = (float)c;
        atomicAdd(&hist[c], 1u);
    }
    __syncthreads();

    float ssum = 0.0f;
#pragma unroll
    for (int p = 0; p < 4; ++p) {
        int rl = p * 4 + w;
        int grow = row0 + rl;
        int bc = bestc_l[rl];
        float4 xv = *reinterpret_cast<const float4*>(&xs[p][w][lane * 4]);
        float4 ev = *reinterpret_cast<const float4*>(emb + (size_t)bc * DDIM + lane * 4);
        float dx = ev.x - xv.x, dy = ev.y - xv.y, dz = ev.z - xv.z, dw = ev.w - xv.w;
        float4 q = make_float4(xv.x + dx, xv.y + dy, xv.z + dz, xv.w + dw);
        *reinterpret_cast<float4*>(qout + (size_t)grow * DDIM + lane * 4) = q;
        float s = dx * dx + dy * dy + dz * dz + dw * dw;
#pragma unroll
        for (int m = 32; m >= 1; m >>= 1) s += __shfl_xor(s, m, 64);
        ssum += s;
    }
    if (lane == 0) lred[w] = ssum;
    __syncthreads();
    if (threadIdx.x == 0)
        loss_part[blockIdx.x] = (lred[0] + lred[1]) + (lred[2] + lred[3]);
}

// ---------------- scalars: vq_loss (reduce partials), perplexity ---------------
__global__ __launch_bounds__(1024) void scalar_kernel(
    const u32* __restrict__ hist, const float* __restrict__ loss_part,
    float* __restrict__ out_loss, float* __restrict__ out_perp) {
    __shared__ double lred[16];
    __shared__ float ered[16];
    int t = threadIdx.x;
    double ls = 0.0;
#pragma unroll
    for (int i = 0; i < RG_BLOCKS / 1024; ++i)
        ls += (double)loss_part[t + i * 1024];
    float p = (float)hist[t] / 65536.0f;
    float es = p * logf(p + 1e-10f);
#pragma unroll
    for (int m = 32; m >= 1; m >>= 1) {
        ls += __shfl_xor(ls, m, 64);
        es += __shfl_xor(es, m, 64);
    }
    if ((t & 63) == 0) { lred[t >> 6] = ls; ered[t >> 6] = es; }
    __syncthreads();
    if (t < 64) {
        double lv = (t < 16) ? lred[t] : 0.0;
        float ev = (t < 16) ? ered[t] : 0.0f;
#pragma unroll
        for (int m = 32; m >= 1; m >>= 1) {
            lv += __shfl_xor(lv, m, 64);
            ev += __shfl_xor(ev, m, 64);
        }
        if (t == 0) {
            *out_perp = expf(-ev);
            double ml = lv / (double)((size_t)NROWS * DDIM);
            *out_loss = (float)(ml * 0.25 + ml);  // beta*commit + delta*embed (equal)
        }
    }
}

extern "C" void kernel_launch(void* const* d_in, const int* in_sizes, int n_in,
                              void* d_out, int out_size, void* d_ws, size_t ws_size,
                              hipStream_t stream) {
    const float* lat = (const float*)d_in[0];
    const float* emb = (const float*)d_in[1];
    float* out = (float*)d_out;
    char* ws = (char*)d_ws;

    u32* cand_cnt = (u32*)ws;                          // 262144 B
    u16* cand = (u16*)(ws + 262144);                   // 2097152 B
    float* row_sq = (float*)(ws + 2359296);            // 262144 B
    float* emb_sq = (float*)(ws + 2621440);            // 4096 B
    u32* hist = (u32*)(ws + 2625536);                  // 4096 B
    float* loss_part = (float*)(ws + 2629632);         // 65536 B
    u16* Apre = (u16*)(ws + 2695168);                  // 67108864 B
    u16* Bpre = (u16*)(ws + 69804032);                 // 1048576 B
    const size_t WS_NEED = 70852608;

    init_kernel<<<256, 256, 0, stream>>>(cand_cnt, hist);
    sqnorm_kernel<<<(NROWS + KCODES) / 4, 256, 0, stream>>>(lat, emb, row_sq, emb_sq);
    if (ws_size >= WS_NEED) {
        convert_kernel<<<(NROWS * 32 + KCODES * 32) / 256, 256, 0, stream>>>(
            lat, emb, Apre, Bpre);
        dist_mfma3_kernel<<<4096, 256, 0, stream>>>(Apre, Bpre, row_sq, emb_sq,
                                                    out + DIST_OFF, cand_cnt, cand);
    } else {
        dim3 grid(KCODES / 128, NROWS / 128);
        dist_mfma_kernel<<<grid, 256, 0, stream>>>(lat, emb, row_sq, emb_sq,
                                                   out + DIST_OFF, cand_cnt, cand);
    }
    refine_gather_kernel<<<RG_BLOCKS, 256, 0, stream>>>(lat, emb, row_sq, emb_sq,
                                                        cand_cnt, cand,
                                                        out + Q_OFF, out + IND_OFF,
                                                        hist, loss_part);
    scalar_kernel<<<1, 1024, 0, stream>>>(hist, loss_part,
                                          out + LOSS_OFF, out + PERP_OFF);
}

// Round 8
// 340.599 us; speedup vs baseline: 1.7145x; 1.0188x over previous
//
#include <hip/hip_runtime.h>

#define NROWS 65536
#define KCODES 1024
#define DDIM 256

// output offsets in floats (concat of reference return tuple)
#define Q_OFF    0
#define LOSS_OFF 16777216
#define PERP_OFF 16777217
#define IND_OFF  16777218
#define DIST_OFF 16842754

#define MARGIN  1.5e-3f
#define MAXCAND 16
#define RG_BLOCKS (NROWS / 16)   // 4096 blocks, 16 rows each

typedef unsigned long long u64;
typedef unsigned int u32;
typedef unsigned short u16;
typedef __attribute__((ext_vector_type(8))) short bf16x8;
typedef __attribute__((ext_vector_type(4))) float f32x4;

// RNE float->bf16 bits (no NaN handling; inputs are tame)
__device__ inline u32 f2bf_bits(float f) {
    u32 u = __float_as_uint(f);
    return (u + 0x7fffu + ((u >> 16) & 1u)) >> 16;
}

__device__ inline void gload16(const void* g, void* l) {
    __builtin_amdgcn_global_load_lds(
        (const __attribute__((address_space(1))) unsigned int*)g,
        (__attribute__((address_space(3))) unsigned int*)l, 16, 0, 0);
}

// ---------------- init workspace ----------------------------------------------
__global__ __launch_bounds__(256) void init_kernel(u32* __restrict__ cand_cnt,
                                                   u32* __restrict__ hist) {
    int i = blockIdx.x * 256 + threadIdx.x;
    if (i < NROWS) cand_cnt[i] = 0u;
    if (i < KCODES) hist[i] = 0u;
}

// ---------------- squared norms (unchanged order -> stable rs/es bits) --------
__global__ __launch_bounds__(256) void sqnorm_kernel(
    const float* __restrict__ lat, const float* __restrict__ emb,
    float* __restrict__ row_sq, float* __restrict__ emb_sq) {
    int gwave = (blockIdx.x * 256 + threadIdx.x) >> 6;
    int lane = threadIdx.x & 63;
    if (gwave >= NROWS + KCODES) return;
    const float* src = (gwave < NROWS) ? lat + (size_t)gwave * DDIM
                                       : emb + (size_t)(gwave - NROWS) * DDIM;
    float4 v = *reinterpret_cast<const float4*>(src + lane * 4);
    float s = v.x * v.x + v.y * v.y + v.z * v.z + v.w * v.w;
#pragma unroll
    for (int m = 32; m >= 1; m >>= 1) s += __shfl_xor(s, m, 64);
    if (lane == 0) {
        if (gwave < NROWS) row_sq[gwave] = s;
        else emb_sq[gwave - NROWS] = s;
    }
}

// -------- fp32 -> bf16 (hi only) into TILED + CHUNK-SWIZZLED layout -----------
// Apre[tile][ks 0..3][r 0..127][chunk 0..7]; chunk = 16B = 8 bf16 covering
// k = c*8..c*8+7 of this 64-wide K-step; logical chunk c stored at c ^ (r&7).
// Global layout == LDS image per K-step (linear global_load_lds; XOR on read).
__global__ __launch_bounds__(256) void convert_kernel(
    const float* __restrict__ lat, const float* __restrict__ emb,
    u16* __restrict__ Apre, u16* __restrict__ Bpre) {
    const int NA_IT = NROWS * 32;   // (rowgroup, ks, c) items
    const int NB_IT = KCODES * 32;
    int g = blockIdx.x * 256 + threadIdx.x;
    if (g >= NA_IT + NB_IT) return;
    const float* src;
    uint4* dst;
    int it;
    if (g < NA_IT) { src = lat; dst = (uint4*)Apre; it = g; }
    else           { src = emb; dst = (uint4*)Bpre; it = g - NA_IT; }
    int c = it & 7, ks = (it >> 3) & 3, rg = it >> 5;
    const float* s = src + (size_t)rg * DDIM + ks * 64 + c * 8;
    float4 v0 = *reinterpret_cast<const float4*>(s);
    float4 v1 = *reinterpret_cast<const float4*>(s + 4);
    u32 h0 = f2bf_bits(v0.x), h1 = f2bf_bits(v0.y), h2 = f2bf_bits(v0.z), h3 = f2bf_bits(v0.w);
    u32 h4 = f2bf_bits(v1.x), h5 = f2bf_bits(v1.y), h6 = f2bf_bits(v1.z), h7 = f2bf_bits(v1.w);
    uint4 hq = make_uint4(h0 | (h1 << 16), h2 | (h3 << 16), h4 | (h5 << 16), h6 | (h7 << 16));
    int r = rg & 127, tile = rg >> 7;
    dst[((size_t)(tile * 4 + ks) * 128 + r) * 8 + (c ^ (r & 7))] = hq;
}

// ---------------- dist: hh-only bf16 MFMA (pruner + output) -------------------
// 128x128 tile, BK=64, 4 K-steps, 4 waves, 32KB LDS, gload_lds staging.
// dist output error <= ~1.6e-3 (threshold 20.48); argmin via refine.
__global__ __launch_bounds__(256, 4) void dist_hh_kernel(
    const u16* __restrict__ Apre, const u16* __restrict__ Bpre,
    const float* __restrict__ row_sq, const float* __restrict__ emb_sq,
    float* __restrict__ dist, u32* __restrict__ cand_cnt, u16* __restrict__ cand) {
    __shared__ u16 Ash[128 * 64];   // 16KB
    __shared__ u16 Bsh[128 * 64];   // 16KB
    const int tid = threadIdx.x;
    const int lane = tid & 63, wid = tid >> 6;
    const int wr = wid >> 1, wc = wid & 1;       // wave quadrant (64x64)
    const int li = lane & 15, lg = lane >> 4;
    // XCD-aware swizzle: each XCD gets contiguous row-tiles (A-panel L2 reuse)
    const int swzb = (blockIdx.x & 7) * 512 + (blockIdx.x >> 3);
    const int rt = swzb >> 3, ct = swzb & 7;
    const int row0 = rt * 128, col0 = ct * 128;

    const char* Ab = (const char*)Apre + (size_t)rt * 65536;
    const char* Bb = (const char*)Bpre + (size_t)ct * 65536;
    char* AshB = (char*)Ash;
    char* BshB = (char*)Bsh;
    const int so = wid * 4096 + lane * 16;   // per-lane global offset
    const int dso = wid * 4096;              // wave-uniform LDS offset

    f32x4 acc[4][4];
#pragma unroll
    for (int mf = 0; mf < 4; ++mf)
#pragma unroll
        for (int nf = 0; nf < 4; ++nf) acc[mf][nf] = (f32x4)0.0f;

    for (int ks = 0; ks < 4; ++ks) {
        __syncthreads();  // previous iter's LDS reads done
        const char* Asrc = Ab + ks * 16384;
        const char* Bsrc = Bb + ks * 16384;
#pragma unroll
        for (int i = 0; i < 4; ++i) {
            gload16(Asrc + so + i * 1024, AshB + dso + i * 1024);
            gload16(Bsrc + so + i * 1024, BshB + dso + i * 1024);
        }
        __syncthreads();  // vmcnt(0) drain: staged data visible
        // fragment reads: row r, k = lg*8 (o) and k = 32+lg*8 (o^64)
        bf16x8 fah[4], fa2[4], fbh[4], fb2[4];
#pragma unroll
        for (int mf = 0; mf < 4; ++mf) {
            int r = wr * 64 + mf * 16 + li;
            int o = r * 128 + ((lg ^ (r & 7)) << 4);
            fah[mf] = *reinterpret_cast<const bf16x8*>(AshB + o);
            fa2[mf] = *reinterpret_cast<const bf16x8*>(AshB + (o ^ 64));
        }
#pragma unroll
        for (int nf = 0; nf < 4; ++nf) {
            int cc = wc * 64 + nf * 16 + li;
            int o = cc * 128 + ((lg ^ (cc & 7)) << 4);
            fbh[nf] = *reinterpret_cast<const bf16x8*>(BshB + o);
            fb2[nf] = *reinterpret_cast<const bf16x8*>(BshB + (o ^ 64));
        }
#pragma unroll
        for (int mf = 0; mf < 4; ++mf)
#pragma unroll
            for (int nf = 0; nf < 4; ++nf) {
                acc[mf][nf] = __builtin_amdgcn_mfma_f32_16x16x32_bf16(fah[mf], fbh[nf], acc[mf][nf], 0, 0, 0);
                acc[mf][nf] = __builtin_amdgcn_mfma_f32_16x16x32_bf16(fa2[mf], fb2[nf], acc[mf][nf], 0, 0, 0);
            }
    }

    // ---------------- epilogue: dist write + block-local row-min + candidates --
    __syncthreads();
    float* rs_lds = reinterpret_cast<float*>(Ash);     // 128 f
    float* es_lds = rs_lds + 128;                      // 128 f
    float* rowmin_lds = es_lds + 128;                  // 128 f
    if (tid < 128) rs_lds[tid] = row_sq[row0 + tid];
    else if (tid < 256) es_lds[tid - 128] = emb_sq[col0 + tid - 128];
    __syncthreads();

    // C/D layout: row = (lane>>4)*4 + reg, col = lane&15 (per 16x16 frag)
    float rmin[16];
#pragma unroll
    for (int mf = 0; mf < 4; ++mf)
#pragma unroll
        for (int rg = 0; rg < 4; ++rg) {
            int rl = wr * 64 + mf * 16 + lg * 4 + rg;
            float rs = rs_lds[rl];
            float best = 3.4e38f;
#pragma unroll
            for (int nf = 0; nf < 4; ++nf) {
                int cl = wc * 64 + nf * 16 + li;
                float dv = (rs + es_lds[cl]) - 2.0f * acc[mf][nf][rg];
                dist[(size_t)(row0 + rl) * KCODES + col0 + cl] = dv;
                best = fminf(best, dv);
            }
            rmin[mf * 4 + rg] = best;
        }
#pragma unroll
    for (int m = 8; m >= 1; m >>= 1)
#pragma unroll
        for (int j = 0; j < 16; ++j) rmin[j] = fminf(rmin[j], __shfl_xor(rmin[j], m, 64));
    if (wc == 0 && li == 0) {
#pragma unroll
        for (int mf = 0; mf < 4; ++mf)
#pragma unroll
            for (int rg = 0; rg < 4; ++rg)
                rowmin_lds[wr * 64 + mf * 16 + lg * 4 + rg] = rmin[mf * 4 + rg];
    }
    __syncthreads();
    if (wc == 1 && li == 0) {
#pragma unroll
        for (int mf = 0; mf < 4; ++mf)
#pragma unroll
            for (int rg = 0; rg < 4; ++rg) {
                int rl = wr * 64 + mf * 16 + lg * 4 + rg;
                rowmin_lds[rl] = fminf(rowmin_lds[rl], rmin[mf * 4 + rg]);
            }
    }
    __syncthreads();
    // candidate recording: dv <= block-row-min + MARGIN (superset of fp32-chain
    // min achievers given MARGIN >= 2*err; overflow handled by refine rescan)
#pragma unroll
    for (int mf = 0; mf < 4; ++mf)
#pragma unroll
        for (int rg = 0; rg < 4; ++rg) {
            int rl = wr * 64 + mf * 16 + lg * 4 + rg;
            float thr = rowmin_lds[rl] + MARGIN;
            float rs = rs_lds[rl];
#pragma unroll
            for (int nf = 0; nf < 4; ++nf) {
                int cl = wc * 64 + nf * 16 + li;
                float dv = (rs + es_lds[cl]) - 2.0f * acc[mf][nf][rg];
                if (dv <= thr) {
                    int grow = row0 + rl;
                    u32 slot = atomicAdd(&cand_cnt[grow], 1u);
                    if (slot < MAXCAND) cand[(size_t)grow * MAXCAND + slot] = (u16)(col0 + cl);
                }
            }
        }
}

// ------- refine: bit-exact fp32 serial-FMA compare; 4 rows/wave, 8-deep MLP ---
// Rare overflow (cnt > MAXCAND) -> full 1024-code rescan with identical chain.
__global__ __launch_bounds__(256) void refine_gather_kernel(
    const float* __restrict__ lat, const float* __restrict__ emb,
    const float* __restrict__ row_sq, const float* __restrict__ emb_sq,
    const u32* __restrict__ cand_cnt, const u16* __restrict__ cand,
    float* __restrict__ qout, float* __restrict__ indout,
    u32* __restrict__ hist, float* __restrict__ loss_part) {
    __shared__ __align__(16) float xs[4][4][260];  // [wave][rowInWave][256+pad]
    __shared__ int bestc_l[16];
    __shared__ float lred[4];
    const int w = threadIdx.x >> 6, lane = threadIdx.x & 63;
    const int rw = lane >> 4, slot = lane & 15;
    const int row0 = blockIdx.x * 16;

#pragma unroll
    for (int rr = 0; rr < 4; ++rr) {
        int row = row0 + w * 4 + rr;
        float4 xv = *reinterpret_cast<const float4*>(lat + (size_t)row * DDIM + lane * 4);
        *reinterpret_cast<float4*>(&xs[w][rr][lane * 4]) = xv;
    }
    __syncthreads();

    const int row = row0 + w * 4 + rw;
    int cntraw = (int)cand_cnt[row];
    int cnt = (cntraw > MAXCAND) ? MAXCAND : cntraw;
    int sl = (slot < cnt) ? slot : 0;   // cnt >= 1 always (block-min recorded)
    int c = cand[(size_t)row * MAXCAND + sl];

    const float* erow = emb + (size_t)c * DDIM;
    float4 e0 = *reinterpret_cast<const float4*>(erow + 0);
    float4 e1 = *reinterpret_cast<const float4*>(erow + 4);
    float4 e2 = *reinterpret_cast<const float4*>(erow + 8);
    float4 e3 = *reinterpret_cast<const float4*>(erow + 12);
    float4 e4 = *reinterpret_cast<const float4*>(erow + 16);
    float4 e5 = *reinterpret_cast<const float4*>(erow + 20);
    float4 e6 = *reinterpret_cast<const float4*>(erow + 24);
    float4 e7 = *reinterpret_cast<const float4*>(erow + 28);
    float acc = 0.0f;
#define STEP(PF, K) { \
        float4 xq = *reinterpret_cast<const float4*>(&xs[w][rw][(K) * 4]); \
        acc = __builtin_fmaf(xq.x, PF.x, acc); \
        acc = __builtin_fmaf(xq.y, PF.y, acc); \
        acc = __builtin_fmaf(xq.z, PF.z, acc); \
        acc = __builtin_fmaf(xq.w, PF.w, acc); \
        if ((K) + 8 < 64) PF = *reinterpret_cast<const float4*>(erow + ((K) + 8) * 4); }
#define GROUP(G) STEP(e0, (G)*8+0) STEP(e1, (G)*8+1) STEP(e2, (G)*8+2) STEP(e3, (G)*8+3) \
                 STEP(e4, (G)*8+4) STEP(e5, (G)*8+5) STEP(e6, (G)*8+6) STEP(e7, (G)*8+7)
    GROUP(0) GROUP(1) GROUP(2) GROUP(3) GROUP(4) GROUP(5) GROUP(6) GROUP(7)
#undef GROUP
#undef STEP
    float t = row_sq[row] + emb_sq[c];
    float dv = __builtin_fmaf(-2.0f, acc, t);   // == t - 2*acc exactly (x2 exact)

    // lexicographic (dv, index) min over the 16 slots of this row
#pragma unroll
    for (int m = 8; m >= 1; m >>= 1) {
        float od = __shfl_xor(dv, m, 64);
        int oc = __shfl_xor(c, m, 64);
        if (od < dv || (od == dv && oc < c)) { dv = od; c = oc; }
    }

    // rare: candidate overflow -> full rescan of this row (all 64 lanes)
    u64 ovm = __ballot(slot == 0 && cntraw > MAXCAND);
    while (ovm) {
        int l = __ffsll((long long)ovm) - 1;
        ovm &= ovm - 1;
        int ow = l >> 4;                  // rw of the overflowing row
        int orow = row0 + w * 4 + ow;
        float tbase = row_sq[orow];
        float bdv = 3.4e38f;
        int bc = KCODES;
        for (int j = 0; j < 16; ++j) {
            int cc = lane + j * 64;
            const float* er = emb + (size_t)cc * DDIM;
            float a2 = 0.0f;
            for (int k4 = 0; k4 < 64; ++k4) {
                float4 ev = *reinterpret_cast<const float4*>(er + k4 * 4);
                float4 xq = *reinterpret_cast<const float4*>(&xs[w][ow][k4 * 4]);
                a2 = __builtin_fmaf(xq.x, ev.x, a2);
                a2 = __builtin_fmaf(xq.y, ev.y, a2);
                a2 = __builtin_fmaf(xq.z, ev.z, a2);
                a2 = __builtin_fmaf(xq.w, ev.w, a2);
            }
            float dv2 = __builtin_fmaf(-2.0f, a2, tbase + emb_sq[cc]);
            if (dv2 < bdv || (dv2 == bdv && cc < bc)) { bdv = dv2; bc = cc; }
        }
#pragma unroll
        for (int m = 32; m >= 1; m >>= 1) {
            float od = __shfl_xor(bdv, m, 64);
            int oc = __shfl_xor(bc, m, 64);
            if (od < bdv || (od == bdv && oc < bc)) { bdv = od; bc = oc; }
        }
        if (rw == ow) { dv = bdv; c = bc; }
    }

    if (slot == 0) {
        bestc_l[w * 4 + rw] = c;
        indout[row] = (float)c;
        atomicAdd(&hist[c], 1u);
    }
    __syncthreads();

    // gather phase: pass p -> wave w handles local row p*4+w == xs[p][w]
    float ssum = 0.0f;
#pragma unroll
    for (int p = 0; p < 4; ++p) {
        int rl = p * 4 + w;
        int grow = row0 + rl;
        int bc = bestc_l[rl];
        float4 xv = *reinterpret_cast<const float4*>(&xs[p][w][lane * 4]);
        float4 ev = *reinterpret_cast<const float4*>(emb + (size_t)bc * DDIM + lane * 4);
        float dx = ev.x - xv.x, dy = ev.y - xv.y, dz = ev.z - xv.z, dw = ev.w - xv.w;
        float4 q = make_float4(xv.x + dx, xv.y + dy, xv.z + dz, xv.w + dw);
        *reinterpret_cast<float4*>(qout + (size_t)grow * DDIM + lane * 4) = q;
        float s = dx * dx + dy * dy + dz * dz + dw * dw;
#pragma unroll
        for (int m = 32; m >= 1; m >>= 1) s += __shfl_xor(s, m, 64);
        ssum += s;
    }
    if (lane == 0) lred[w] = ssum;
    __syncthreads();
    if (threadIdx.x == 0)
        loss_part[blockIdx.x] = (lred[0] + lred[1]) + (lred[2] + lred[3]);
}

// ---------------- scalars: vq_loss (reduce partials), perplexity ---------------
__global__ __launch_bounds__(1024) void scalar_kernel(
    const u32* __restrict__ hist, const float* __restrict__ loss_part,
    float* __restrict__ out_loss, float* __restrict__ out_perp) {
    __shared__ double lred[16];
    __shared__ float ered[16];
    int t = threadIdx.x;
    double ls = 0.0;
#pragma unroll
    for (int i = 0; i < RG_BLOCKS / 1024; ++i)
        ls += (double)loss_part[t + i * 1024];
    float p = (float)hist[t] / 65536.0f;
    float es = p * logf(p + 1e-10f);
#pragma unroll
    for (int m = 32; m >= 1; m >>= 1) {
        ls += __shfl_xor(ls, m, 64);
        es += __shfl_xor(es, m, 64);
    }
    if ((t & 63) == 0) { lred[t >> 6] = ls; ered[t >> 6] = es; }
    __syncthreads();
    if (t < 64) {
        double lv = (t < 16) ? lred[t] : 0.0;
        float ev = (t < 16) ? ered[t] : 0.0f;
#pragma unroll
        for (int m = 32; m >= 1; m >>= 1) {
            lv += __shfl_xor(lv, m, 64);
            ev += __shfl_xor(ev, m, 64);
        }
        if (t == 0) {
            *out_perp = expf(-ev);
            double ml = lv / (double)((size_t)NROWS * DDIM);
            *out_loss = (float)(ml * 0.25 + ml);  // beta*commit + delta*embed (equal)
        }
    }
}

extern "C" void kernel_launch(void* const* d_in, const int* in_sizes, int n_in,
                              void* d_out, int out_size, void* d_ws, size_t ws_size,
                              hipStream_t stream) {
    const float* lat = (const float*)d_in[0];
    const float* emb = (const float*)d_in[1];
    float* out = (float*)d_out;
    char* ws = (char*)d_ws;

    u32* cand_cnt = (u32*)ws;                          // 262144 B
    u16* cand = (u16*)(ws + 262144);                   // 2097152 B
    float* row_sq = (float*)(ws + 2359296);            // 262144 B
    float* emb_sq = (float*)(ws + 2621440);            // 4096 B
    u32* hist = (u32*)(ws + 2625536);                  // 4096 B
    float* loss_part = (float*)(ws + 2629632);         // 16384 B
    u16* Apre = (u16*)(ws + 2695168);                  // 33554432 B
    u16* Bpre = (u16*)(ws + 36249600);                 // 524288 B

    init_kernel<<<256, 256, 0, stream>>>(cand_cnt, hist);
    sqnorm_kernel<<<(NROWS + KCODES) / 4, 256, 0, stream>>>(lat, emb, row_sq, emb_sq);
    convert_kernel<<<(NROWS * 32 + KCODES * 32) / 256, 256, 0, stream>>>(
        lat, emb, Apre, Bpre);
    dist_hh_kernel<<<4096, 256, 0, stream>>>(Apre, Bpre, row_sq, emb_sq,
                                             out + DIST_OFF, cand_cnt, cand);
    refine_gather_kernel<<<RG_BLOCKS, 256, 0, stream>>>(lat, emb, row_sq, emb_sq,
                                                        cand_cnt, cand,
                                                        out + Q_OFF, out + IND_OFF,
                                                        hist, loss_part);
    scalar_kernel<<<1, 1024, 0, stream>>>(hist, loss_part,
                                          out + LOSS_OFF, out + PERP_OFF);
}

// Round 9
// 337.406 us; speedup vs baseline: 1.7307x; 1.0095x over previous
//
#include <hip/hip_runtime.h>

#define NROWS 65536
#define KCODES 1024
#define DDIM 256

// output offsets in floats (concat of reference return tuple)
#define Q_OFF    0
#define LOSS_OFF 16777216
#define PERP_OFF 16777217
#define IND_OFF  16777218
#define DIST_OFF 16842754

#define MARGIN  1.5e-3f
#define MAXCAND 16
#define RG_BLOCKS (NROWS / 16)   // 4096 blocks, 16 rows each

typedef unsigned long long u64;
typedef unsigned int u32;
typedef unsigned short u16;
typedef __attribute__((ext_vector_type(8))) short bf16x8;
typedef __attribute__((ext_vector_type(4))) float f32x4;

// RNE float->bf16 bits (no NaN handling; inputs are tame)
__device__ inline u32 f2bf_bits(float f) {
    u32 u = __float_as_uint(f);
    return (u + 0x7fffu + ((u >> 16) & 1u)) >> 16;
}

__device__ inline void gload16(const void* g, void* l) {
    __builtin_amdgcn_global_load_lds(
        (const __attribute__((address_space(1))) unsigned int*)g,
        (__attribute__((address_space(3))) unsigned int*)l, 16, 0, 0);
}

// ---------------- init workspace ----------------------------------------------
__global__ __launch_bounds__(256) void init_kernel(u32* __restrict__ cand_cnt,
                                                   u32* __restrict__ hist) {
    int i = blockIdx.x * 256 + threadIdx.x;
    if (i < NROWS) cand_cnt[i] = 0u;
    if (i < KCODES) hist[i] = 0u;
}

// ---------------- squared norms (unchanged order -> stable rs/es bits) --------
__global__ __launch_bounds__(256) void sqnorm_kernel(
    const float* __restrict__ lat, const float* __restrict__ emb,
    float* __restrict__ row_sq, float* __restrict__ emb_sq) {
    int gwave = (blockIdx.x * 256 + threadIdx.x) >> 6;
    int lane = threadIdx.x & 63;
    if (gwave >= NROWS + KCODES) return;
    const float* src = (gwave < NROWS) ? lat + (size_t)gwave * DDIM
                                       : emb + (size_t)(gwave - NROWS) * DDIM;
    float4 v = *reinterpret_cast<const float4*>(src + lane * 4);
    float s = v.x * v.x + v.y * v.y + v.z * v.z + v.w * v.w;
#pragma unroll
    for (int m = 32; m >= 1; m >>= 1) s += __shfl_xor(s, m, 64);
    if (lane == 0) {
        if (gwave < NROWS) row_sq[gwave] = s;
        else emb_sq[gwave - NROWS] = s;
    }
}

// -------- fp32 -> bf16 (hi only) into TILED + CHUNK-SWIZZLED layout -----------
// Apre[tile][ks 0..3][r 0..127][chunk 0..7]; chunk = 16B = 8 bf16 covering
// k = c*8..c*8+7 of this 64-wide K-step; logical chunk c stored at c ^ (r&7).
__global__ __launch_bounds__(256) void convert_kernel(
    const float* __restrict__ lat, const float* __restrict__ emb,
    u16* __restrict__ Apre, u16* __restrict__ Bpre) {
    const int NA_IT = NROWS * 32;   // (rowgroup, ks, c) items
    const int NB_IT = KCODES * 32;
    int g = blockIdx.x * 256 + threadIdx.x;
    if (g >= NA_IT + NB_IT) return;
    const float* src;
    uint4* dst;
    int it;
    if (g < NA_IT) { src = lat; dst = (uint4*)Apre; it = g; }
    else           { src = emb; dst = (uint4*)Bpre; it = g - NA_IT; }
    int c = it & 7, ks = (it >> 3) & 3, rg = it >> 5;
    const float* s = src + (size_t)rg * DDIM + ks * 64 + c * 8;
    float4 v0 = *reinterpret_cast<const float4*>(s);
    float4 v1 = *reinterpret_cast<const float4*>(s + 4);
    u32 h0 = f2bf_bits(v0.x), h1 = f2bf_bits(v0.y), h2 = f2bf_bits(v0.z), h3 = f2bf_bits(v0.w);
    u32 h4 = f2bf_bits(v1.x), h5 = f2bf_bits(v1.y), h6 = f2bf_bits(v1.z), h7 = f2bf_bits(v1.w);
    uint4 hq = make_uint4(h0 | (h1 << 16), h2 | (h3 << 16), h4 | (h5 << 16), h6 | (h7 << 16));
    int r = rg & 127, tile = rg >> 7;
    dst[((size_t)(tile * 4 + ks) * 128 + r) * 8 + (c ^ (r & 7))] = hq;
}

// ---------------- dist: hh-only bf16 MFMA + LDS-transposed wide stores --------
// 128x128 tile, BK=64, 4 K-steps, 4 waves, gload_lds staging. Epilogue
// transposes dv through LDS so stores are dwordx4 (16/thread vs 64 scalar).
__global__ __launch_bounds__(256, 4) void dist_hh_kernel(
    const u16* __restrict__ Apre, const u16* __restrict__ Bpre,
    const float* __restrict__ row_sq, const float* __restrict__ emb_sq,
    float* __restrict__ dist, u32* __restrict__ cand_cnt, u16* __restrict__ cand) {
    __shared__ __align__(16) char smem[64 * 132 * 4 + 1536];  // 35328 B
    char* AshB = smem;                                  // 16KB staging A
    char* BshB = smem + 16384;                          // 16KB staging B
    float* tr = reinterpret_cast<float*>(smem);         // 64x132 epilogue transpose
    float* rs_lds = reinterpret_cast<float*>(smem + 33792);   // 128 f
    float* es_lds = rs_lds + 128;                       // 128 f
    float* rowmin_lds = es_lds + 128;                   // 128 f

    const int tid = threadIdx.x;
    const int lane = tid & 63, wid = tid >> 6;
    const int wr = wid >> 1, wc = wid & 1;       // wave quadrant (64x64)
    const int li = lane & 15, lg = lane >> 4;
    // XCD-aware swizzle: each XCD gets contiguous row-tiles (A-panel L2 reuse)
    const int swzb = (blockIdx.x & 7) * 512 + (blockIdx.x >> 3);
    const int rt = swzb >> 3, ct = swzb & 7;
    const int row0 = rt * 128, col0 = ct * 128;

    const char* Ab = (const char*)Apre + (size_t)rt * 65536;
    const char* Bb = (const char*)Bpre + (size_t)ct * 65536;
    const int so = wid * 4096 + lane * 16;   // per-lane global offset
    const int dso = wid * 4096;              // wave-uniform LDS offset

    f32x4 acc[4][4];
#pragma unroll
    for (int mf = 0; mf < 4; ++mf)
#pragma unroll
        for (int nf = 0; nf < 4; ++nf) acc[mf][nf] = (f32x4)0.0f;

    for (int ks = 0; ks < 4; ++ks) {
        __syncthreads();  // previous iter's LDS reads done
        const char* Asrc = Ab + ks * 16384;
        const char* Bsrc = Bb + ks * 16384;
#pragma unroll
        for (int i = 0; i < 4; ++i) {
            gload16(Asrc + so + i * 1024, AshB + dso + i * 1024);
            gload16(Bsrc + so + i * 1024, BshB + dso + i * 1024);
        }
        __syncthreads();  // vmcnt(0) drain: staged data visible
        // fragment reads: row r, k = lg*8 (o) and k = 32+lg*8 (o^64)
        bf16x8 fah[4], fa2[4], fbh[4], fb2[4];
#pragma unroll
        for (int mf = 0; mf < 4; ++mf) {
            int r = wr * 64 + mf * 16 + li;
            int o = r * 128 + ((lg ^ (r & 7)) << 4);
            fah[mf] = *reinterpret_cast<const bf16x8*>(AshB + o);
            fa2[mf] = *reinterpret_cast<const bf16x8*>(AshB + (o ^ 64));
        }
#pragma unroll
        for (int nf = 0; nf < 4; ++nf) {
            int cc = wc * 64 + nf * 16 + li;
            int o = cc * 128 + ((lg ^ (cc & 7)) << 4);
            fbh[nf] = *reinterpret_cast<const bf16x8*>(BshB + o);
            fb2[nf] = *reinterpret_cast<const bf16x8*>(BshB + (o ^ 64));
        }
#pragma unroll
        for (int mf = 0; mf < 4; ++mf)
#pragma unroll
            for (int nf = 0; nf < 4; ++nf) {
                acc[mf][nf] = __builtin_amdgcn_mfma_f32_16x16x32_bf16(fah[mf], fbh[nf], acc[mf][nf], 0, 0, 0);
                acc[mf][nf] = __builtin_amdgcn_mfma_f32_16x16x32_bf16(fa2[mf], fb2[nf], acc[mf][nf], 0, 0, 0);
            }
    }

    // ---------------- epilogue ------------------------------------------------
    __syncthreads();                         // staging LDS now dead
    if (tid < 128) rs_lds[tid] = row_sq[row0 + tid];
    else if (tid < 256) es_lds[tid - 128] = emb_sq[col0 + tid - 128];
    __syncthreads();

    float es4[4];
#pragma unroll
    for (int nf = 0; nf < 4; ++nf) es4[nf] = es_lds[wc * 64 + nf * 16 + li];

    // C/D layout: row = (lane>>4)*4 + reg, col = lane&15 (per 16x16 frag)
    float rmin[16];
    // two passes: pass p handles global rows row0 + p*64 .. +63
#pragma unroll
    for (int p = 0; p < 2; ++p) {
        if (wr == p) {
#pragma unroll
            for (int mf = 0; mf < 4; ++mf)
#pragma unroll
                for (int rg = 0; rg < 4; ++rg) {
                    int rl2 = mf * 16 + lg * 4 + rg;          // 0..63
                    float rs = rs_lds[p * 64 + rl2];
                    float best = 3.4e38f;
#pragma unroll
                    for (int nf = 0; nf < 4; ++nf) {
                        float dv = (rs + es4[nf]) - 2.0f * acc[mf][nf][rg];
                        tr[rl2 * 132 + wc * 64 + nf * 16 + li] = dv;
                        best = fminf(best, dv);
                    }
                    rmin[mf * 4 + rg] = best;
                }
        }
        __syncthreads();
        // all waves: linear LDS read -> dwordx4 stores (contiguous 512B/row)
#pragma unroll
        for (int k = 0; k < 8; ++k) {
            int idx = tid + k * 256;
            int r2 = idx >> 5, c4 = idx & 31;
            float4 v = *reinterpret_cast<const float4*>(&tr[r2 * 132 + c4 * 4]);
            *reinterpret_cast<float4*>(
                dist + (size_t)(row0 + p * 64 + r2) * KCODES + col0 + c4 * 4) = v;
        }
        __syncthreads();   // before next pass overwrites tr
    }

    // row-min reduce across the 16 li lanes
#pragma unroll
    for (int m = 8; m >= 1; m >>= 1)
#pragma unroll
        for (int j = 0; j < 16; ++j) rmin[j] = fminf(rmin[j], __shfl_xor(rmin[j], m, 64));
    if (wc == 0 && li == 0) {
#pragma unroll
        for (int mf = 0; mf < 4; ++mf)
#pragma unroll
            for (int rg = 0; rg < 4; ++rg)
                rowmin_lds[wr * 64 + mf * 16 + lg * 4 + rg] = rmin[mf * 4 + rg];
    }
    __syncthreads();
    if (wc == 1 && li == 0) {
#pragma unroll
        for (int mf = 0; mf < 4; ++mf)
#pragma unroll
            for (int rg = 0; rg < 4; ++rg) {
                int rl = wr * 64 + mf * 16 + lg * 4 + rg;
                rowmin_lds[rl] = fminf(rowmin_lds[rl], rmin[mf * 4 + rg]);
            }
    }
    __syncthreads();
    // candidate recording: dv <= block-row-min + MARGIN (superset of fp32-chain
    // min achievers given MARGIN >= 2*err; overflow handled by refine rescan)
#pragma unroll
    for (int mf = 0; mf < 4; ++mf)
#pragma unroll
        for (int rg = 0; rg < 4; ++rg) {
            int rl = wr * 64 + mf * 16 + lg * 4 + rg;
            float thr = rowmin_lds[rl] + MARGIN;
            float rs = rs_lds[rl];
#pragma unroll
            for (int nf = 0; nf < 4; ++nf) {
                int cl = wc * 64 + nf * 16 + li;
                float dv = (rs + es4[nf]) - 2.0f * acc[mf][nf][rg];
                if (dv <= thr) {
                    int grow = row0 + rl;
                    u32 slot = atomicAdd(&cand_cnt[grow], 1u);
                    if (slot < MAXCAND) cand[(size_t)grow * MAXCAND + slot] = (u16)(col0 + cl);
                }
            }
        }
}

// ------- refine: bit-exact fp32 serial-FMA compare; 4 rows/wave, 8-deep MLP ---
// Rare overflow (cnt > MAXCAND) -> full 1024-code rescan with identical chain.
__global__ __launch_bounds__(256) void refine_gather_kernel(
    const float* __restrict__ lat, const float* __restrict__ emb,
    const float* __restrict__ row_sq, const float* __restrict__ emb_sq,
    const u32* __restrict__ cand_cnt, const u16* __restrict__ cand,
    float* __restrict__ qout, float* __restrict__ indout,
    u32* __restrict__ hist, float* __restrict__ loss_part) {
    __shared__ __align__(16) float xs[4][4][260];  // [wave][rowInWave][256+pad]
    __shared__ int bestc_l[16];
    __shared__ float lred[4];
    const int w = threadIdx.x >> 6, lane = threadIdx.x & 63;
    const int rw = lane >> 4, slot = lane & 15;
    const int row0 = blockIdx.x * 16;

#pragma unroll
    for (int rr = 0; rr < 4; ++rr) {
        int row = row0 + w * 4 + rr;
        float4 xv = *reinterpret_cast<const float4*>(lat + (size_t)row * DDIM + lane * 4);
        *reinterpret_cast<float4*>(&xs[w][rr][lane * 4]) = xv;
    }
    __syncthreads();

    const int row = row0 + w * 4 + rw;
    int cntraw = (int)cand_cnt[row];
    int cnt = (cntraw > MAXCAND) ? MAXCAND : cntraw;
    int sl = (slot < cnt) ? slot : 0;   // cnt >= 1 always (block-min is recorded)
    int c = cand[(size_t)row * MAXCAND + sl];

    const float* erow = emb + (size_t)c * DDIM;
    float4 e0 = *reinterpret_cast<const float4*>(erow + 0);
    float4 e1 = *reinterpret_cast<const float4*>(erow + 4);
    float4 e2 = *reinterpret_cast<const float4*>(erow + 8);
    float4 e3 = *reinterpret_cast<const float4*>(erow + 12);
    float4 e4 = *reinterpret_cast<const float4*>(erow + 16);
    float4 e5 = *reinterpret_cast<const float4*>(erow + 20);
    float4 e6 = *reinterpret_cast<const float4*>(erow + 24);
    float4 e7 = *reinterpret_cast<const float4*>(erow + 28);
    float acc = 0.0f;
#define STEP(PF, K) { \
        float4 xq = *reinterpret_cast<const float4*>(&xs[w][rw][(K) * 4]); \
        acc = __builtin_fmaf(xq.x, PF.x, acc); \
        acc = __builtin_fmaf(xq.y, PF.y, acc); \
        acc = __builtin_fmaf(xq.z, PF.z, acc); \
        acc = __builtin_fmaf(xq.w, PF.w, acc); \
        if ((K) + 8 < 64) PF = *reinterpret_cast<const float4*>(erow + ((K) + 8) * 4); }
#define GROUP(G) STEP(e0, (G)*8+0) STEP(e1, (G)*8+1) STEP(e2, (G)*8+2) STEP(e3, (G)*8+3) \
                 STEP(e4, (G)*8+4) STEP(e5, (G)*8+5) STEP(e6, (G)*8+6) STEP(e7, (G)*8+7)
    GROUP(0) GROUP(1) GROUP(2) GROUP(3) GROUP(4) GROUP(5) GROUP(6) GROUP(7)
#undef GROUP
#undef STEP
    float t = row_sq[row] + emb_sq[c];
    float dv = __builtin_fmaf(-2.0f, acc, t);   // == t - 2*acc exactly (x2 exact)

    // lexicographic (dv, index) min over the 16 slots of this row
#pragma unroll
    for (int m = 8; m >= 1; m >>= 1) {
        float od = __shfl_xor(dv, m, 64);
        int oc = __shfl_xor(c, m, 64);
        if (od < dv || (od == dv && oc < c)) { dv = od; c = oc; }
    }

    // rare: candidate overflow -> full rescan of this row (all 64 lanes)
    u64 ovm = __ballot(slot == 0 && cntraw > MAXCAND);
    while (ovm) {
        int l = __ffsll((long long)ovm) - 1;
        ovm &= ovm - 1;
        int ow = l >> 4;                  // rw of the overflowing row
        int orow = row0 + w * 4 + ow;
        float tbase = row_sq[orow];
        float bdv = 3.4e38f;
        int bc = KCODES;
        for (int j = 0; j < 16; ++j) {
            int cc = lane + j * 64;
            const float* er = emb + (size_t)cc * DDIM;
            float a2 = 0.0f;
            for (int k4 = 0; k4 < 64; ++k4) {
                float4 ev = *reinterpret_cast<const float4*>(er + k4 * 4);
                float4 xq = *reinterpret_cast<const float4*>(&xs[w][ow][k4 * 4]);
                a2 = __builtin_fmaf(xq.x, ev.x, a2);
                a2 = __builtin_fmaf(xq.y, ev.y, a2);
                a2 = __builtin_fmaf(xq.z, ev.z, a2);
                a2 = __builtin_fmaf(xq.w, ev.w, a2);
            }
            float dv2 = __builtin_fmaf(-2.0f, a2, tbase + emb_sq[cc]);
            if (dv2 < bdv || (dv2 == bdv && cc < bc)) { bdv = dv2; bc = cc; }
        }
#pragma unroll
        for (int m = 32; m >= 1; m >>= 1) {
            float od = __shfl_xor(bdv, m, 64);
            int oc = __shfl_xor(bc, m, 64);
            if (od < bdv || (od == bdv && oc < bc)) { bdv = od; bc = oc; }
        }
        if (rw == ow) { dv = bdv; c = bc; }
    }

    if (slot == 0) {
        bestc_l[w * 4 + rw] = c;
        indout[row] = (float)c;
        atomicAdd(&hist[c], 1u);
    }
    __syncthreads();

    // gather phase: pass p -> wave w handles local row p*4+w == xs[p][w]
    float ssum = 0.0f;
#pragma unroll
    for (int p = 0; p < 4; ++p) {
        int rl = p * 4 + w;
        int grow = row0 + rl;
        int bc = bestc_l[rl];
        float4 xv = *reinterpret_cast<const float4*>(&xs[p][w][lane * 4]);
        float4 ev = *reinterpret_cast<const float4*>(emb + (size_t)bc * DDIM + lane * 4);
        float dx = ev.x - xv.x, dy = ev.y - xv.y, dz = ev.z - xv.z, dw = ev.w - xv.w;
        float4 q = make_float4(xv.x + dx, xv.y + dy, xv.z + dz, xv.w + dw);
        *reinterpret_cast<float4*>(qout + (size_t)grow * DDIM + lane * 4) = q;
        float s = dx * dx + dy * dy + dz * dz + dw * dw;
#pragma unroll
        for (int m = 32; m >= 1; m >>= 1) s += __shfl_xor(s, m, 64);
        ssum += s;
    }
    if (lane == 0) lred[w] = ssum;
    __syncthreads();
    if (threadIdx.x == 0)
        loss_part[blockIdx.x] = (lred[0] + lred[1]) + (lred[2] + lred[3]);
}

// ---------------- scalars: vq_loss (reduce partials), perplexity ---------------
__global__ __launch_bounds__(1024) void scalar_kernel(
    const u32* __restrict__ hist, const float* __restrict__ loss_part,
    float* __restrict__ out_loss, float* __restrict__ out_perp) {
    __shared__ double lred[16];
    __shared__ float ered[16];
    int t = threadIdx.x;
    double ls = 0.0;
#pragma unroll
    for (int i = 0; i < RG_BLOCKS / 1024; ++i)
        ls += (double)loss_part[t + i * 1024];
    float p = (float)hist[t] / 65536.0f;
    float es = p * logf(p + 1e-10f);
#pragma unroll
    for (int m = 32; m >= 1; m >>= 1) {
        ls += __shfl_xor(ls, m, 64);
        es += __shfl_xor(es, m, 64);
    }
    if ((t & 63) == 0) { lred[t >> 6] = ls; ered[t >> 6] = es; }
    __syncthreads();
    if (t < 64) {
        double lv = (t < 16) ? lred[t] : 0.0;
        float ev = (t < 16) ? ered[t] : 0.0f;
#pragma unroll
        for (int m = 32; m >= 1; m >>= 1) {
            lv += __shfl_xor(lv, m, 64);
            ev += __shfl_xor(ev, m, 64);
        }
        if (t == 0) {
            *out_perp = expf(-ev);
            double ml = lv / (double)((size_t)NROWS * DDIM);
            *out_loss = (float)(ml * 0.25 + ml);  // beta*commit + delta*embed (equal)
        }
    }
}

extern "C" void kernel_launch(void* const* d_in, const int* in_sizes, int n_in,
                              void* d_out, int out_size, void* d_ws, size_t ws_size,
                              hipStream_t stream) {
    const float* lat = (const float*)d_in[0];
    const float* emb = (const float*)d_in[1];
    float* out = (float*)d_out;
    char* ws = (char*)d_ws;

    u32* cand_cnt = (u32*)ws;                          // 262144 B
    u16* cand = (u16*)(ws + 262144);                   // 2097152 B
    float* row_sq = (float*)(ws + 2359296);            // 262144 B
    float* emb_sq = (float*)(ws + 2621440);            // 4096 B
    u32* hist = (u32*)(ws + 2625536);                  // 4096 B
    float* loss_part = (float*)(ws + 2629632);         // 16384 B
    u16* Apre = (u16*)(ws + 2695168);                  // 33554432 B
    u16* Bpre = (u16*)(ws + 36249600);                 // 524288 B

    init_kernel<<<256, 256, 0, stream>>>(cand_cnt, hist);
    sqnorm_kernel<<<(NROWS + KCODES) / 4, 256, 0, stream>>>(lat, emb, row_sq, emb_sq);
    convert_kernel<<<(NROWS * 32 + KCODES * 32) / 256, 256, 0, stream>>>(
        lat, emb, Apre, Bpre);
    dist_hh_kernel<<<4096, 256, 0, stream>>>(Apre, Bpre, row_sq, emb_sq,
                                             out + DIST_OFF, cand_cnt, cand);
    refine_gather_kernel<<<RG_BLOCKS, 256, 0, stream>>>(lat, emb, row_sq, emb_sq,
                                                        cand_cnt, cand,
                                                        out + Q_OFF, out + IND_OFF,
                                                        hist, loss_part);
    scalar_kernel<<<1, 1024, 0, stream>>>(hist, loss_part,
                                          out + LOSS_OFF, out + PERP_OFF);
}